// Round 1
// baseline (1300.473 us; speedup 1.0000x reference)
//
#include <hip/hip_runtime.h>
#include <hip/hip_bf16.h>

// Problem: HydraAttention  B=8 N=16384 C=256 NH=8 CH=32 H=W=128
// Pipeline:
//   K1  qkv = x @ w_qkv          -> qT, kT, vT  (bf16, channel-major [b][c][n])
//   K1b kv[b,h,c] = sum_n kn*v   (k normalized per token over CH)
//   K2  crpe depthwise conv + hydra combine -> midT (bf16, channel-major)
//   K3  out = mid @ w_proj + b_proj  (fp32 row-major)
// kT aliases midT (k dead after K1b, mid written in K2).

typedef __hip_bfloat16 bf16;

#define B_ 8
#define N_ 16384
#define C_ 256
#define NH_ 8
#define CH_ 32
#define HW_ 128
#define SCALE_ 0.17677669529663687f

// ---------------------------------------------------------------- K1: qkv GEMM
// grid (12, 2048), block 256.  Tile: 64 out-cols (j) x 64 tokens, BK=16.
// Thread (tx,ty): tx = token quad (4 consecutive n), ty = j quad.
// Output written transposed: X_t[b][j][n] (bf16), 8B stores, 128B runs/16 lanes.
__global__ __launch_bounds__(256) void qkv_gemm(
    const float* __restrict__ x, const float* __restrict__ wqkv,
    bf16* __restrict__ qT, bf16* __restrict__ kT, bf16* __restrict__ vT) {
  __shared__ float Ws[16][68];  // [kk][jr]
  __shared__ float Xs[16][68];  // [kk][tt]
  const int tid = threadIdx.x;
  const int j0 = blockIdx.x * 64;
  const long t0 = (long)blockIdx.y * 64;
  const int b = (int)(t0 >> 14);
  const int n0 = (int)(t0 & (N_ - 1));
  const int tx = tid & 15;   // token quad
  const int ty = tid >> 4;   // j quad
  float acc[4][4];           // [jr][tt]
#pragma unroll
  for (int i = 0; i < 4; ++i)
#pragma unroll
    for (int j = 0; j < 4; ++j) acc[i][j] = 0.f;

  for (int k0 = 0; k0 < 256; k0 += 16) {
#pragma unroll
    for (int i = 0; i < 4; ++i) {          // stage W tile (coalesced over j)
      int e = tid + i * 256;
      int jr = e & 63, kk = e >> 6;
      Ws[kk][jr] = wqkv[(k0 + kk) * 768 + j0 + jr];
    }
#pragma unroll
    for (int i = 0; i < 4; ++i) {          // stage x tile (kk fastest, 64B segs)
      int e = tid + i * 256;
      int kk = e & 15, tt = e >> 4;
      Xs[kk][tt] = x[(t0 + tt) * 256 + k0 + kk];
    }
    __syncthreads();
#pragma unroll
    for (int kk = 0; kk < 16; ++kk) {
      float4 wv = *(const float4*)&Ws[kk][ty * 4];
      float4 xv = *(const float4*)&Xs[kk][tx * 4];
      float wa[4] = {wv.x, wv.y, wv.z, wv.w};
      float xa[4] = {xv.x, xv.y, xv.z, xv.w};
#pragma unroll
      for (int a = 0; a < 4; ++a)
#pragma unroll
        for (int t = 0; t < 4; ++t) acc[a][t] += wa[a] * xa[t];
    }
    __syncthreads();
  }

  const int region = j0 >> 8;  // 0:q 1:k 2:v  (block never straddles regions)
  bf16* outp = (region == 0) ? qT : ((region == 1) ? kT : vT);
  const int jj0 = (j0 & 255) + ty * 4;
  const int nn0 = n0 + tx * 4;
#pragma unroll
  for (int jr = 0; jr < 4; ++jr) {
    bf16 pack[4];
#pragma unroll
    for (int t = 0; t < 4; ++t) pack[t] = __float2bfloat16(acc[jr][t]);
    *(uint2*)&outp[((size_t)b * C_ + jj0 + jr) * N_ + nn0] = *(uint2*)pack;
  }
}

// ------------------------------------------------------------ K1b: kv reduce
// grid (16, 64), block 256. blockIdx.y = b*8+h. Each thread owns 4 tokens.
__global__ __launch_bounds__(256) void kv_reduce(
    const bf16* __restrict__ kT, const bf16* __restrict__ vT,
    float* __restrict__ kv) {
  const int tid = threadIdx.x;
  const int bh = blockIdx.y;
  const int b = bh >> 3, h = bh & 7;
  const size_t base = ((size_t)b * C_ + h * CH_) * N_;
  const bf16* kp = kT + base;
  const bf16* vp = vT + base;
  float partial[32];
#pragma unroll
  for (int c = 0; c < 32; ++c) partial[c] = 0.f;

  for (int it = 0; it < 4; ++it) {
    const int n = blockIdx.x * 1024 + it * 256 + tid;
    float kreg[32];
    float ss = 0.f;
#pragma unroll
    for (int c = 0; c < 32; ++c) {
      float kvl = __bfloat162float(kp[(size_t)c * N_ + n]);
      kreg[c] = kvl;
      ss += kvl * kvl;
    }
    const float inv = rsqrtf(ss);
#pragma unroll
    for (int c = 0; c < 32; ++c)
      partial[c] += kreg[c] * inv * __bfloat162float(vp[(size_t)c * N_ + n]);
  }
#pragma unroll
  for (int c = 0; c < 32; ++c) {
#pragma unroll
    for (int off = 32; off >= 1; off >>= 1)
      partial[c] += __shfl_xor(partial[c], off);
  }
  if ((tid & 63) == 0) {
#pragma unroll
    for (int c = 0; c < 32; ++c) atomicAdd(&kv[bh * 32 + c], partial[c]);
  }
}

// ------------------------------------------------- K2: crpe conv + combine
// grid (8, 8, 64), block 256 = 16x16 pixel tile. blockIdx.z = b*8+h.
// Loops 32 channels; per channel stages v tile+halo in LDS, convs, combines.
__global__ __launch_bounds__(256) void crpe_combine(
    const bf16* __restrict__ qT, const bf16* __restrict__ vT,
    const float* __restrict__ kv,
    const float* __restrict__ w3, const float* __restrict__ b3,
    const float* __restrict__ w5, const float* __restrict__ b5,
    const float* __restrict__ w7, const float* __restrict__ b7,
    bf16* __restrict__ midT) {
  __shared__ float vs[22 * 22];
  __shared__ float wk[49];
  const int tid = threadIdx.x;
  const int bh = blockIdx.z;
  const int b = bh >> 3, h = bh & 7;
  const int x0 = blockIdx.x * 16, y0 = blockIdx.y * 16;
  const int px = tid & 15, py = tid >> 4;
  const int n = (y0 + py) * HW_ + (x0 + px);

  int K, OC, ocbase;
  const float *wp, *bp;
  if (h < 2)      { K = 3; OC = 64; ocbase = h * 32;       wp = w3; bp = b3; }
  else if (h < 5) { K = 5; OC = 96; ocbase = (h - 2) * 32; wp = w5; bp = b5; }
  else            { K = 7; OC = 96; ocbase = (h - 5) * 32; wp = w7; bp = b7; }
  const int R = K >> 1, S = 16 + 2 * R;

  const size_t base = ((size_t)b * C_ + h * CH_) * N_;
  const bf16* qp = qT + base;
  const bf16* vp = vT + base;

  // q-norm prepass (sum of squares over the 32 channels of this head)
  float ss = 0.f;
#pragma unroll
  for (int c = 0; c < 32; ++c) {
    float qv = __bfloat162float(qp[(size_t)c * N_ + n]);
    ss += qv * qv;
  }
  const float qinv = rsqrtf(ss);

  for (int c = 0; c < 32; ++c) {
    const int oc = ocbase + c;
    __syncthreads();  // protect LDS from previous iteration
    for (int e = tid; e < S * S; e += 256) {
      int ly = e / S, lx = e - ly * S;
      int gyy = y0 - R + ly, gxx = x0 - R + lx;
      float v = 0.f;
      if (gyy >= 0 && gyy < HW_ && gxx >= 0 && gxx < HW_)
        v = __bfloat162float(vp[(size_t)c * N_ + gyy * HW_ + gxx]);
      vs[e] = v;
    }
    if (tid < K * K) wk[tid] = wp[tid * OC + oc];
    __syncthreads();

    float cv = bp[oc];
    for (int ky = 0; ky < K; ++ky)
      for (int kx = 0; kx < K; ++kx)
        cv += wk[ky * K + kx] * vs[(py + ky) * S + (px + kx)];

    const float qv = __bfloat162float(qp[(size_t)c * N_ + n]);
    const float o = SCALE_ * qv * qinv * kv[bh * 32 + c] + qv * cv;
    midT[base + (size_t)c * N_ + n] = __float2bfloat16(o);
  }
}

// ---------------------------------------------------------------- K3: proj GEMM
// grid (4, 2048), block 256. Tile 64 tokens x 64 j, BK=16.
// tx = j quad (fp32 float4 row-major stores), ty = token quad.
__global__ __launch_bounds__(256) void proj_gemm(
    const bf16* __restrict__ midT, const float* __restrict__ wproj,
    const float* __restrict__ bproj, float* __restrict__ out) {
  __shared__ float As[16][68];  // [kk][tt]
  __shared__ float Bs[16][68];  // [kk][jj]
  const int tid = threadIdx.x;
  const int j0 = blockIdx.x * 64;
  const long t0 = (long)blockIdx.y * 64;
  const int b = (int)(t0 >> 14);
  const int n0 = (int)(t0 & (N_ - 1));
  const int tx = tid & 15;  // j quad
  const int ty = tid >> 4;  // token quad
  float acc[4][4];          // [t][j]
#pragma unroll
  for (int i = 0; i < 4; ++i)
#pragma unroll
    for (int j = 0; j < 4; ++j) acc[i][j] = 0.f;

  for (int k0 = 0; k0 < 256; k0 += 16) {
#pragma unroll
    for (int i = 0; i < 4; ++i) {  // stage mid tile (coalesced over tokens)
      int e = tid + i * 256;
      int tt = e & 63, kk = e >> 6;
      As[kk][tt] =
          __bfloat162float(midT[((size_t)b * C_ + k0 + kk) * N_ + n0 + tt]);
    }
#pragma unroll
    for (int i = 0; i < 4; ++i) {  // stage w_proj tile (coalesced over j)
      int e = tid + i * 256;
      int jj = e & 63, kk = e >> 6;
      Bs[kk][jj] = wproj[(k0 + kk) * 256 + j0 + jj];
    }
    __syncthreads();
#pragma unroll
    for (int kk = 0; kk < 16; ++kk) {
      float4 av = *(const float4*)&As[kk][ty * 4];
      float4 bv = *(const float4*)&Bs[kk][tx * 4];
      float aa[4] = {av.x, av.y, av.z, av.w};
      float bb[4] = {bv.x, bv.y, bv.z, bv.w};
#pragma unroll
      for (int t = 0; t < 4; ++t)
#pragma unroll
        for (int j = 0; j < 4; ++j) acc[t][j] += aa[t] * bb[j];
    }
    __syncthreads();
  }

  float4 bias = *(const float4*)&bproj[j0 + tx * 4];
#pragma unroll
  for (int t = 0; t < 4; ++t) {
    float4 r;
    r.x = acc[t][0] + bias.x;
    r.y = acc[t][1] + bias.y;
    r.z = acc[t][2] + bias.z;
    r.w = acc[t][3] + bias.w;
    *(float4*)&out[(t0 + ty * 4 + t) * 256 + j0 + tx * 4] = r;
  }
}

// ------------------------------------------------------------------- launcher
extern "C" void kernel_launch(void* const* d_in, const int* in_sizes, int n_in,
                              void* d_out, int out_size, void* d_ws,
                              size_t ws_size, hipStream_t stream) {
  const float* x     = (const float*)d_in[0];
  const float* wqkv  = (const float*)d_in[1];
  const float* wproj = (const float*)d_in[2];
  const float* bproj = (const float*)d_in[3];
  const float* w3 = (const float*)d_in[4];
  const float* b3 = (const float*)d_in[5];
  const float* w5 = (const float*)d_in[6];
  const float* b5 = (const float*)d_in[7];
  const float* w7 = (const float*)d_in[8];
  const float* b7 = (const float*)d_in[9];
  float* out = (float*)d_out;

  const size_t PLANE = (size_t)B_ * C_ * N_;  // 33,554,432 elems
  bf16* qT   = (bf16*)d_ws;        // 64 MiB
  bf16* vT   = qT + PLANE;         // 64 MiB
  bf16* midT = vT + PLANE;         // 64 MiB (k lives here first, then mid)
  bf16* kT   = midT;               // alias: k dead after kv_reduce
  float* kv  = (float*)(midT + PLANE);  // 2048 floats

  hipMemsetAsync(kv, 0, B_ * NH_ * CH_ * sizeof(float), stream);
  qkv_gemm<<<dim3(12, 2048), 256, 0, stream>>>(x, wqkv, qT, kT, vT);
  kv_reduce<<<dim3(16, 64), 256, 0, stream>>>(kT, vT, kv);
  crpe_combine<<<dim3(8, 8, 64), 256, 0, stream>>>(qT, vT, kv, w3, b3, w5, b5,
                                                   w7, b7, midT);
  proj_gemm<<<dim3(4, 2048), 256, 0, stream>>>(midT, wproj, bproj, out);
}

// Round 2
// 576.142 us; speedup vs baseline: 2.2572x; 2.2572x over previous
//
#include <hip/hip_runtime.h>
#include <hip/hip_bf16.h>

// HydraAttention  B=8 N=16384 C=256 NH=8 CH=32 H=W=128
// K0  prep: wqkvT[j][k], wprojT[j][k] bf16 transposed weights
// K1  qkv_mfma: qkv = x @ w_qkv -> qT,kT,vT channel-major bf16 [b][c][n]
// K1b kv_reduce: kv[b,h,c] = sum_n kn*v
// K2  crpe_combine: depthwise conv + hydra combine -> mid token-major bf16
// K3  proj_mfma: out = mid @ w_proj + b_proj (fp32 row-major)

typedef __hip_bfloat16 bf16;
typedef __bf16 bf16x8 __attribute__((ext_vector_type(8)));
typedef unsigned short u16x8 __attribute__((ext_vector_type(8)));
typedef float f32x4 __attribute__((ext_vector_type(4)));

#define SCALE_ 0.17677669529663687f
#define HW_ 128

__device__ __forceinline__ unsigned short f2b(float f) {
  __hip_bfloat16 h = __float2bfloat16(f);
  return __builtin_bit_cast(unsigned short, h);
}

__device__ __forceinline__ void gload16(const void* g, void* l) {
  __builtin_amdgcn_global_load_lds(
      (const __attribute__((address_space(1))) unsigned int*)g,
      (__attribute__((address_space(3))) unsigned int*)l, 16, 0, 0);
}

__device__ __forceinline__ f32x4 mfma16(u16x8 a, u16x8 b, f32x4 c) {
  return __builtin_amdgcn_mfma_f32_16x16x32_bf16(
      __builtin_bit_cast(bf16x8, a), __builtin_bit_cast(bf16x8, b), c, 0, 0, 0);
}

// ------------------------------------------------------------- weight prep
__global__ __launch_bounds__(256) void prep_weights(
    const float* __restrict__ wqkv, const float* __restrict__ wproj,
    bf16* __restrict__ wqkvT, bf16* __restrict__ wprojT) {
  const int idx = blockIdx.x * 256 + threadIdx.x;
  if (idx < 768 * 256) {
    const int j = idx >> 8, k = idx & 255;
    wqkvT[idx] = __float2bfloat16(wqkv[k * 768 + j]);
  }
  if (idx < 256 * 256) {
    const int j = idx >> 8, k = idx & 255;
    wprojT[idx] = __float2bfloat16(wproj[k * 256 + j]);
  }
}

// --------------------------------------------------------------- K1: qkv MFMA
// grid (6, 1024), block 256 (4 waves). Tile 128 j x 128 tokens, BK=32.
// A = x[token][k] (fp32 -> bf16 reg-staged); B = wqkvT[j][k] via global_load_lds.
// LDS tiles [row][32k] with 16B-slot XOR swizzle: slot' = slot ^ (row&3).
__global__ __launch_bounds__(256) void qkv_mfma(
    const float* __restrict__ x, const bf16* __restrict__ wT,
    bf16* __restrict__ qT, bf16* __restrict__ kT, bf16* __restrict__ vT) {
  __shared__ __align__(16) char As[8192];
  __shared__ __align__(16) char Bs[8192];
  const int tid = threadIdx.x;
  const int l = tid & 63, w = tid >> 6;
  const int wr = w >> 1, wc = w & 1;        // wr: token half, wc: j half
  const int j0 = blockIdx.x << 7;
  const int t0 = blockIdx.y << 7;

  f32x4 acc[4][4];
#pragma unroll
  for (int m = 0; m < 4; ++m)
#pragma unroll
    for (int n = 0; n < 4; ++n) acc[m][n] = (f32x4){0.f, 0.f, 0.f, 0.f};

  // A reg-staging: thread covers (row = tid>>1, k-half = tid&1) = 16 floats
  const int arow = tid >> 1, akh = tid & 1;
  const float* xp = x + (size_t)(t0 + arow) * 256 + akh * 16;
  char* awr0 = As + arow * 64 + (((akh << 1) ^ (arow & 3)) << 4);
  char* awr1 = As + arow * 64 + ((((akh << 1) | 1) ^ (arow & 3)) << 4);

  // B staging via global_load_lds: wave w, shots cover rows w*16.. and +64
  const int brow0 = w * 16 + (l >> 2), brow1 = brow0 + 64;
  const int bsl = l & 3;
  const bf16* bsrc0 = wT + (size_t)(j0 + brow0) * 256 + ((bsl ^ (brow0 & 3)) << 3);
  const bf16* bsrc1 = wT + (size_t)(j0 + brow1) * 256 + ((bsl ^ (brow1 & 3)) << 3);
  char* bdst0 = Bs + w * 1024;
  char* bdst1 = Bs + 4096 + w * 1024;

  const int fr = l & 15;
  const int fs = ((l >> 4) ^ (l & 3)) << 4;   // swizzled fragment slot byte

  for (int k0 = 0; k0 < 256; k0 += 32) {
    const float4 xa0 = *(const float4*)(xp + k0);
    const float4 xa1 = *(const float4*)(xp + k0 + 4);
    const float4 xa2 = *(const float4*)(xp + k0 + 8);
    const float4 xa3 = *(const float4*)(xp + k0 + 12);
    __syncthreads();  // prev iteration's LDS reads done
    u16x8 p0, p1;
    p0[0] = f2b(xa0.x); p0[1] = f2b(xa0.y); p0[2] = f2b(xa0.z); p0[3] = f2b(xa0.w);
    p0[4] = f2b(xa1.x); p0[5] = f2b(xa1.y); p0[6] = f2b(xa1.z); p0[7] = f2b(xa1.w);
    p1[0] = f2b(xa2.x); p1[1] = f2b(xa2.y); p1[2] = f2b(xa2.z); p1[3] = f2b(xa2.w);
    p1[4] = f2b(xa3.x); p1[5] = f2b(xa3.y); p1[6] = f2b(xa3.z); p1[7] = f2b(xa3.w);
    *(u16x8*)awr0 = p0;
    *(u16x8*)awr1 = p1;
    gload16(bsrc0 + k0, bdst0);
    gload16(bsrc1 + k0, bdst1);
    __syncthreads();  // drains vmcnt+lgkmcnt
    u16x8 af[4], bfv[4];
#pragma unroll
    for (int m = 0; m < 4; ++m)
      af[m] = *(const u16x8*)(As + (wr * 64 + m * 16 + fr) * 64 + fs);
#pragma unroll
    for (int n = 0; n < 4; ++n)
      bfv[n] = *(const u16x8*)(Bs + (wc * 64 + n * 16 + fr) * 64 + fs);
#pragma unroll
    for (int m = 0; m < 4; ++m)
#pragma unroll
      for (int n = 0; n < 4; ++n)
        acc[m][n] = mfma16(af[m], bfv[n], acc[m][n]);
  }

  const int region = blockIdx.x >> 1;  // 0:q 1:k 2:v (128-tile never straddles)
  bf16* outp = (region == 0) ? qT : ((region == 1) ? kT : vT);
  const int b = t0 >> 14;
  const int nbase = (t0 & 16383) + wr * 64 + (l >> 4) * 4;
#pragma unroll
  for (int m = 0; m < 4; ++m) {
#pragma unroll
    for (int n = 0; n < 4; ++n) {
      const int jj = (j0 & 255) + wc * 64 + n * 16 + fr;
      uint2 pk;
      pk.x = (unsigned)f2b(acc[m][n][0]) | ((unsigned)f2b(acc[m][n][1]) << 16);
      pk.y = (unsigned)f2b(acc[m][n][2]) | ((unsigned)f2b(acc[m][n][3]) << 16);
      *(uint2*)&outp[((size_t)b * 256 + jj) * 16384 + nbase + m * 16] = pk;
    }
  }
}

// ------------------------------------------------------------ K1b: kv reduce
__global__ __launch_bounds__(256) void kv_reduce(
    const bf16* __restrict__ kT, const bf16* __restrict__ vT,
    float* __restrict__ kv) {
  const int tid = threadIdx.x;
  const int bh = blockIdx.y;
  const int b = bh >> 3, h = bh & 7;
  const size_t base = ((size_t)b * 256 + h * 32) * 16384;
  const bf16* kp = kT + base;
  const bf16* vp = vT + base;
  float partial[32];
#pragma unroll
  for (int c = 0; c < 32; ++c) partial[c] = 0.f;

  for (int it = 0; it < 4; ++it) {
    const int n = blockIdx.x * 1024 + it * 256 + tid;
    float kreg[32];
    float ss = 0.f;
#pragma unroll
    for (int c = 0; c < 32; ++c) {
      float kvl = __bfloat162float(kp[(size_t)c * 16384 + n]);
      kreg[c] = kvl;
      ss += kvl * kvl;
    }
    const float inv = rsqrtf(ss);
#pragma unroll
    for (int c = 0; c < 32; ++c)
      partial[c] += kreg[c] * inv * __bfloat162float(vp[(size_t)c * 16384 + n]);
  }
#pragma unroll
  for (int c = 0; c < 32; ++c) {
#pragma unroll
    for (int off = 32; off >= 1; off >>= 1)
      partial[c] += __shfl_xor(partial[c], off);
  }
  if ((tid & 63) == 0) {
#pragma unroll
    for (int c = 0; c < 32; ++c) atomicAdd(&kv[bh * 32 + c], partial[c]);
  }
}

// ------------------------------------------------- K2: crpe conv + combine
// grid (8, 8, 64), block 256 = 16x16 pixel tile. Writes mid TOKEN-major:
// per thread 32 contiguous bf16 channels (64B vector stores).
__global__ __launch_bounds__(256) void crpe_combine(
    const bf16* __restrict__ qT, const bf16* __restrict__ vT,
    const float* __restrict__ kv,
    const float* __restrict__ w3, const float* __restrict__ b3,
    const float* __restrict__ w5, const float* __restrict__ b5,
    const float* __restrict__ w7, const float* __restrict__ b7,
    bf16* __restrict__ mid) {
  __shared__ float vs[22 * 22];
  __shared__ float wk[49];
  const int tid = threadIdx.x;
  const int bh = blockIdx.z;
  const int b = bh >> 3, h = bh & 7;
  const int x0 = blockIdx.x * 16, y0 = blockIdx.y * 16;
  const int px = tid & 15, py = tid >> 4;
  const int n = (y0 + py) * HW_ + (x0 + px);

  int K, OC, ocbase;
  const float *wp, *bp;
  if (h < 2)      { K = 3; OC = 64; ocbase = h * 32;       wp = w3; bp = b3; }
  else if (h < 5) { K = 5; OC = 96; ocbase = (h - 2) * 32; wp = w5; bp = b5; }
  else            { K = 7; OC = 96; ocbase = (h - 5) * 32; wp = w7; bp = b7; }
  const int R = K >> 1, S = 16 + 2 * R;

  const size_t base = ((size_t)b * 256 + h * 32) * 16384;
  const bf16* qp = qT + base;
  const bf16* vp = vT + base;

  // hoisted q reads + q-norm
  float qreg[32];
  float ss = 0.f;
#pragma unroll
  for (int c = 0; c < 32; ++c) {
    qreg[c] = __bfloat162float(qp[(size_t)c * 16384 + n]);
    ss += qreg[c] * qreg[c];
  }
  const float qinv = rsqrtf(ss);

  for (int c = 0; c < 32; ++c) {
    const int oc = ocbase + c;
    __syncthreads();
    for (int e = tid; e < S * S; e += 256) {
      int ly = e / S, lx = e - ly * S;
      int gyy = y0 - R + ly, gxx = x0 - R + lx;
      float v = 0.f;
      if (gyy >= 0 && gyy < HW_ && gxx >= 0 && gxx < HW_)
        v = __bfloat162float(vp[(size_t)c * 16384 + gyy * HW_ + gxx]);
      vs[e] = v;
    }
    if (tid < K * K) wk[tid] = wp[tid * OC + oc];
    __syncthreads();

    float cv = bp[oc];
    for (int ky = 0; ky < K; ++ky)
      for (int kx = 0; kx < K; ++kx)
        cv += wk[ky * K + kx] * vs[(py + ky) * S + (px + kx)];

    qreg[c] = SCALE_ * qreg[c] * qinv * kv[bh * 32 + c] + qreg[c] * cv;
  }

  const size_t obase = ((size_t)b * 16384 + n) * 256 + h * 32;
#pragma unroll
  for (int g = 0; g < 4; ++g) {
    u16x8 pv;
#pragma unroll
    for (int i = 0; i < 8; ++i) pv[i] = f2b(qreg[g * 8 + i]);
    *(u16x8*)&mid[obase + g * 8] = pv;
  }
}

// --------------------------------------------------------------- K3: proj MFMA
// grid (2, 1024), block 256. M=j (rows), N=token (cols), K=256, BK=32.
// A = wprojT[j][k]; B = mid[token][k] (token-major). Both via global_load_lds.
// D: col=lane&15=token, row=j -> float4 stores to out[token][j].
__global__ __launch_bounds__(256) void proj_mfma(
    const bf16* __restrict__ mid, const bf16* __restrict__ wpT,
    const float* __restrict__ bproj, float* __restrict__ out) {
  __shared__ __align__(16) char As[8192];
  __shared__ __align__(16) char Bs[8192];
  const int tid = threadIdx.x;
  const int l = tid & 63, w = tid >> 6;
  const int wr = w >> 1, wc = w & 1;  // wr: j half, wc: token half
  const int j0 = blockIdx.x << 7;
  const int tk0 = blockIdx.y << 7;

  f32x4 acc[4][4];
#pragma unroll
  for (int m = 0; m < 4; ++m)
#pragma unroll
    for (int t = 0; t < 4; ++t) acc[m][t] = (f32x4){0.f, 0.f, 0.f, 0.f};

  const int row0 = w * 16 + (l >> 2), row1 = row0 + 64;
  const int sl = l & 3;
  const bf16* asrc0 = wpT + (size_t)(j0 + row0) * 256 + ((sl ^ (row0 & 3)) << 3);
  const bf16* asrc1 = wpT + (size_t)(j0 + row1) * 256 + ((sl ^ (row1 & 3)) << 3);
  const bf16* bsrc0 = mid + (size_t)(tk0 + row0) * 256 + ((sl ^ (row0 & 3)) << 3);
  const bf16* bsrc1 = mid + (size_t)(tk0 + row1) * 256 + ((sl ^ (row1 & 3)) << 3);
  char* adst0 = As + w * 1024;
  char* adst1 = As + 4096 + w * 1024;
  char* bdst0 = Bs + w * 1024;
  char* bdst1 = Bs + 4096 + w * 1024;

  const int fr = l & 15;
  const int fs = ((l >> 4) ^ (l & 3)) << 4;

  for (int k0 = 0; k0 < 256; k0 += 32) {
    __syncthreads();
    gload16(asrc0 + k0, adst0);
    gload16(asrc1 + k0, adst1);
    gload16(bsrc0 + k0, bdst0);
    gload16(bsrc1 + k0, bdst1);
    __syncthreads();
    u16x8 af[4], bfv[4];
#pragma unroll
    for (int m = 0; m < 4; ++m)
      af[m] = *(const u16x8*)(As + (wr * 64 + m * 16 + fr) * 64 + fs);
#pragma unroll
    for (int t = 0; t < 4; ++t)
      bfv[t] = *(const u16x8*)(Bs + (wc * 64 + t * 16 + fr) * 64 + fs);
#pragma unroll
    for (int m = 0; m < 4; ++m)
#pragma unroll
      for (int t = 0; t < 4; ++t)
        acc[m][t] = mfma16(af[m], bfv[t], acc[m][t]);
  }

  const int fq = l >> 4;
#pragma unroll
  for (int m = 0; m < 4; ++m) {
    const int j = j0 + wr * 64 + m * 16 + fq * 4;
    const float4 bias = *(const float4*)&bproj[j];
#pragma unroll
    for (int t = 0; t < 4; ++t) {
      const int token = tk0 + wc * 64 + t * 16 + fr;
      float4 r;
      r.x = acc[m][t][0] + bias.x;
      r.y = acc[m][t][1] + bias.y;
      r.z = acc[m][t][2] + bias.z;
      r.w = acc[m][t][3] + bias.w;
      *(float4*)&out[(size_t)token * 256 + j] = r;
    }
  }
}

// ------------------------------------------------------------------- launcher
extern "C" void kernel_launch(void* const* d_in, const int* in_sizes, int n_in,
                              void* d_out, int out_size, void* d_ws,
                              size_t ws_size, hipStream_t stream) {
  const float* x     = (const float*)d_in[0];
  const float* wqkv  = (const float*)d_in[1];
  const float* wproj = (const float*)d_in[2];
  const float* bproj = (const float*)d_in[3];
  const float* w3 = (const float*)d_in[4];
  const float* b3 = (const float*)d_in[5];
  const float* w5 = (const float*)d_in[6];
  const float* b5 = (const float*)d_in[7];
  const float* w7 = (const float*)d_in[8];
  const float* b7 = (const float*)d_in[9];
  float* out = (float*)d_out;

  const size_t PLANE = (size_t)8 * 256 * 16384;  // 33,554,432 bf16
  bf16* qT  = (bf16*)d_ws;            // 64 MiB
  bf16* vT  = qT + PLANE;             // 64 MiB
  bf16* kT  = vT + PLANE;             // 64 MiB; mid aliases (k dead after kv)
  bf16* mid = kT;
  float* kv = (float*)(kT + PLANE);   // 8 KB
  bf16* wqkvT  = (bf16*)(kv + 2048);  // 384 KB
  bf16* wprojT = wqkvT + 768 * 256;   // 128 KB

  hipMemsetAsync(kv, 0, 2048 * sizeof(float), stream);
  prep_weights<<<dim3(768), 256, 0, stream>>>(wqkv, wproj, wqkvT, wprojT);
  qkv_mfma<<<dim3(6, 1024), 256, 0, stream>>>(x, wqkvT, qT, kT, vT);
  kv_reduce<<<dim3(16, 64), 256, 0, stream>>>(kT, vT, kv);
  crpe_combine<<<dim3(8, 8, 64), 256, 0, stream>>>(qT, vT, kv, w3, b3, w5, b5,
                                                   w7, b7, mid);
  proj_mfma<<<dim3(2, 1024), 256, 0, stream>>>(mid, wprojT, bproj, out);
}

// Round 3
// 450.886 us; speedup vs baseline: 2.8843x; 1.2778x over previous
//
#include <hip/hip_runtime.h>
#include <hip/hip_bf16.h>

// HydraAttention  B=8 N=16384 C=256 NH=8 CH=32 H=W=128
// All intermediates TOKEN-major: q,k,v,mid = [b][n][C] bf16 (64B head slices).
// K0  prep: wqkvT[j][k], wprojT[j][k] bf16 transposed weights
// K1  qkv_mfma: A=wqkvT(j rows) x B=x(tokens) -> q,k,v token-major
// K1b kv_reduce: kv[b,h,c] = sum_n kn*v   (token-major 64B slice reads)
// K2  crpe<K>: stage 32ch v tile+halo in LDS (swizzled), conv+combine -> mid
// K3  proj_mfma: out = mid @ w_proj + b_proj (fp32 row-major)

typedef __hip_bfloat16 bf16;
typedef __bf16 bf16x8 __attribute__((ext_vector_type(8)));
typedef unsigned short u16x8 __attribute__((ext_vector_type(8)));
typedef float f32x4 __attribute__((ext_vector_type(4)));
typedef float f32x8 __attribute__((ext_vector_type(8)));

#define SCALE_ 0.17677669529663687f

__device__ __forceinline__ unsigned short f2b(float f) {
  __hip_bfloat16 h = __float2bfloat16(f);
  return __builtin_bit_cast(unsigned short, h);
}
__device__ __forceinline__ float blo(unsigned u) {
  return __builtin_bit_cast(float, u << 16);
}
__device__ __forceinline__ float bhi(unsigned u) {
  return __builtin_bit_cast(float, u & 0xffff0000u);
}
__device__ __forceinline__ f32x8 unpack8(uint4 u) {
  f32x8 r;
  r[0] = blo(u.x); r[1] = bhi(u.x); r[2] = blo(u.y); r[3] = bhi(u.y);
  r[4] = blo(u.z); r[5] = bhi(u.z); r[6] = blo(u.w); r[7] = bhi(u.w);
  return r;
}
__device__ __forceinline__ uint4 pack8(float a0, float a1, float a2, float a3,
                                       float a4, float a5, float a6, float a7) {
  uint4 s;
  s.x = (unsigned)f2b(a0) | ((unsigned)f2b(a1) << 16);
  s.y = (unsigned)f2b(a2) | ((unsigned)f2b(a3) << 16);
  s.z = (unsigned)f2b(a4) | ((unsigned)f2b(a5) << 16);
  s.w = (unsigned)f2b(a6) | ((unsigned)f2b(a7) << 16);
  return s;
}
__device__ __forceinline__ void gload16(const void* g, void* l) {
  __builtin_amdgcn_global_load_lds(
      (const __attribute__((address_space(1))) unsigned int*)g,
      (__attribute__((address_space(3))) unsigned int*)l, 16, 0, 0);
}
__device__ __forceinline__ f32x4 mfma16(u16x8 a, u16x8 b, f32x4 c) {
  return __builtin_amdgcn_mfma_f32_16x16x32_bf16(
      __builtin_bit_cast(bf16x8, a), __builtin_bit_cast(bf16x8, b), c, 0, 0, 0);
}

// ------------------------------------------------------------- weight prep
__global__ __launch_bounds__(256) void prep_weights(
    const float* __restrict__ wqkv, const float* __restrict__ wproj,
    bf16* __restrict__ wqkvT, bf16* __restrict__ wprojT) {
  const int idx = blockIdx.x * 256 + threadIdx.x;
  if (idx < 768 * 256) {
    const int j = idx >> 8, k = idx & 255;
    wqkvT[idx] = __float2bfloat16(wqkv[k * 768 + j]);
  }
  if (idx < 256 * 256) {
    const int j = idx >> 8, k = idx & 255;
    wprojT[idx] = __float2bfloat16(wproj[k * 256 + j]);
  }
}

// --------------------------------------------------------------- K1: qkv MFMA
// grid (6, 1024), block 256 (4 waves). M=j(128 rows), N=tokens(128), BK=32.
// A = wqkvT[j][k] via global_load_lds (inverse-swizzled source);
// B = x[token][k] fp32 -> bf16 reg-staged. D rows=j -> token-major 8B stores.
__global__ __launch_bounds__(256) void qkv_mfma(
    const float* __restrict__ x, const bf16* __restrict__ wT,
    bf16* __restrict__ qO, bf16* __restrict__ kO, bf16* __restrict__ vO) {
  __shared__ __align__(16) char As[8192];
  __shared__ __align__(16) char Bs[8192];
  const int tid = threadIdx.x;
  const int l = tid & 63, w = tid >> 6;
  const int wr = w >> 1, wc = w & 1;  // wr: j half, wc: token half
  const int j0 = blockIdx.x << 7;
  const int t0 = blockIdx.y << 7;

  f32x4 acc[4][4];
#pragma unroll
  for (int m = 0; m < 4; ++m)
#pragma unroll
    for (int t = 0; t < 4; ++t) acc[m][t] = (f32x4){0.f, 0.f, 0.f, 0.f};

  // A staging (gload16): wave w shot rows w*16.. and +64, source pre-swizzled
  const int arow0 = w * 16 + (l >> 2), arow1 = arow0 + 64;
  const int asl = l & 3;
  const bf16* asrc0 = wT + (size_t)(j0 + arow0) * 256 + ((asl ^ (arow0 & 3)) << 3);
  const bf16* asrc1 = wT + (size_t)(j0 + arow1) * 256 + ((asl ^ (arow1 & 3)) << 3);
  char* adst0 = As + w * 1024;
  char* adst1 = As + 4096 + w * 1024;

  // B reg-staging: thread covers (token row = tid>>1, k-half = tid&1)
  const int brow = tid >> 1, bkh = tid & 1;
  const float* xp = x + (size_t)(t0 + brow) * 256 + bkh * 16;
  char* bwr0 = Bs + brow * 64 + (((bkh << 1) ^ (brow & 3)) << 4);
  char* bwr1 = Bs + brow * 64 + ((((bkh << 1) | 1) ^ (brow & 3)) << 4);

  const int fr = l & 15;
  const int fs = ((l >> 4) ^ (l & 3)) << 4;  // swizzled fragment slot byte

  for (int k0 = 0; k0 < 256; k0 += 32) {
    const float4 xa0 = *(const float4*)(xp + k0);
    const float4 xa1 = *(const float4*)(xp + k0 + 4);
    const float4 xa2 = *(const float4*)(xp + k0 + 8);
    const float4 xa3 = *(const float4*)(xp + k0 + 12);
    __syncthreads();  // prev iteration's LDS reads done
    u16x8 p0, p1;
    p0[0] = f2b(xa0.x); p0[1] = f2b(xa0.y); p0[2] = f2b(xa0.z); p0[3] = f2b(xa0.w);
    p0[4] = f2b(xa1.x); p0[5] = f2b(xa1.y); p0[6] = f2b(xa1.z); p0[7] = f2b(xa1.w);
    p1[0] = f2b(xa2.x); p1[1] = f2b(xa2.y); p1[2] = f2b(xa2.z); p1[3] = f2b(xa2.w);
    p1[4] = f2b(xa3.x); p1[5] = f2b(xa3.y); p1[6] = f2b(xa3.z); p1[7] = f2b(xa3.w);
    *(u16x8*)bwr0 = p0;
    *(u16x8*)bwr1 = p1;
    gload16(asrc0 + k0, adst0);
    gload16(asrc1 + k0, adst1);
    __syncthreads();  // drains vmcnt+lgkmcnt
    u16x8 af[4], bfv[4];
#pragma unroll
    for (int m = 0; m < 4; ++m)
      af[m] = *(const u16x8*)(As + (wr * 64 + m * 16 + fr) * 64 + fs);
#pragma unroll
    for (int t = 0; t < 4; ++t)
      bfv[t] = *(const u16x8*)(Bs + (wc * 64 + t * 16 + fr) * 64 + fs);
#pragma unroll
    for (int m = 0; m < 4; ++m)
#pragma unroll
      for (int t = 0; t < 4; ++t)
        acc[m][t] = mfma16(af[m], bfv[t], acc[m][t]);
  }

  const int region = blockIdx.x >> 1;  // 0:q 1:k 2:v
  bf16* outp = (region == 0) ? qO : ((region == 1) ? kO : vO);
  const int b = t0 >> 14;
  const int n0 = (t0 & 16383) + wc * 64;
  const int fq = l >> 4;
  const int jl = (j0 & 255) + wr * 64;
#pragma unroll
  for (int m = 0; m < 4; ++m) {
    const int j = jl + m * 16 + fq * 4;
#pragma unroll
    for (int t = 0; t < 4; ++t) {
      const int n = n0 + t * 16 + fr;
      uint2 pk;
      pk.x = (unsigned)f2b(acc[m][t][0]) | ((unsigned)f2b(acc[m][t][1]) << 16);
      pk.y = (unsigned)f2b(acc[m][t][2]) | ((unsigned)f2b(acc[m][t][3]) << 16);
      *(uint2*)&outp[((size_t)b * 16384 + n) * 256 + j] = pk;
    }
  }
}

// ------------------------------------------------------------ K1b: kv reduce
// grid (16, 64), block 256. bh = blockIdx.y. Token-major 64B slice reads.
__global__ __launch_bounds__(256) void kv_reduce(
    const bf16* __restrict__ kT, const bf16* __restrict__ vT,
    float* __restrict__ kv) {
  const int tid = threadIdx.x;
  const int bh = blockIdx.y;
  const int b = bh >> 3, h = bh & 7;
  f32x8 part[4];
#pragma unroll
  for (int cc = 0; cc < 4; ++cc) part[cc] = (f32x8)0.f;

  for (int it = 0; it < 4; ++it) {
    const int n = blockIdx.x * 1024 + it * 256 + tid;
    const size_t off = ((size_t)b * 16384 + n) * 256 + h * 32;
    const uint4* kp = (const uint4*)(kT + off);
    const uint4* vp = (const uint4*)(vT + off);
    f32x8 kf[4];
    float ss = 0.f;
#pragma unroll
    for (int cc = 0; cc < 4; ++cc) {
      kf[cc] = unpack8(kp[cc]);
#pragma unroll
      for (int i = 0; i < 8; ++i) ss += kf[cc][i] * kf[cc][i];
    }
    const float inv = rsqrtf(ss);
#pragma unroll
    for (int cc = 0; cc < 4; ++cc) {
      f32x8 vf = unpack8(vp[cc]);
#pragma unroll
      for (int i = 0; i < 8; ++i) part[cc][i] += kf[cc][i] * inv * vf[cc ? i : i];
    }
  }
#pragma unroll
  for (int cc = 0; cc < 4; ++cc)
#pragma unroll
    for (int i = 0; i < 8; ++i) {
      float p = part[cc][i];
#pragma unroll
      for (int off = 32; off >= 1; off >>= 1) p += __shfl_xor(p, off);
      part[cc][i] = p;
    }
  if ((tid & 63) == 0) {
#pragma unroll
    for (int cc = 0; cc < 4; ++cc)
#pragma unroll
      for (int i = 0; i < 8; ++i)
        atomicAdd(&kv[bh * 32 + cc * 8 + i], part[cc][i]);
  }
}

// ------------------------------------------------- K2: crpe conv + combine
// template<K>. grid (HEADS, 64, 8): x=head-in-group, y=tile(8x8), z=b.
// Block = 256 threads = 16x16 pixels. LDS: v tile+halo, 32ch bf16 per pixel
// (4x 16B slots, swizzle slot = 4p + (j ^ ((p>>1)&3))), + weights fp32.
template <int K>
__global__ __launch_bounds__(256) void crpe_conv(
    const bf16* __restrict__ qT, const bf16* __restrict__ vT,
    const float* __restrict__ kvbuf, const float* __restrict__ wp,
    const float* __restrict__ bp, int OC, int hbase,
    bf16* __restrict__ mid) {
  constexpr int R = K / 2;
  constexpr int S = 16 + 2 * R;
  constexpr int NSLOT = 4 * ((S - 1) * 23 + 1);
  __shared__ __align__(16) char vs[NSLOT * 16];
  __shared__ float wlds[K * K * 32];
  __shared__ float blds[32];

  const int tid = threadIdx.x;
  const int hg = blockIdx.x;
  const int h = hbase + hg;
  const int tile = blockIdx.y;
  const int b = blockIdx.z;
  const int tx0 = (tile & 7) * 16, ty0 = (tile >> 3) * 16;
  const int px = tid & 15, py = tid >> 4;
  const int ocbase = hg * 32;

  // ---- stage v tile + halo (32 ch/pixel, 64B) with slot swizzle
  for (int e = tid; e < S * S; e += 256) {
    const int ly = e / S, lx = e - ly * S;
    const int gy = ty0 - R + ly, gx = tx0 - R + lx;
    uint4 d0 = {0, 0, 0, 0}, d1 = {0, 0, 0, 0}, d2 = {0, 0, 0, 0},
          d3 = {0, 0, 0, 0};
    if (gy >= 0 && gy < 128 && gx >= 0 && gx < 128) {
      const uint4* src = (const uint4*)(vT +
          ((size_t)b * 16384 + gy * 128 + gx) * 256 + h * 32);
      d0 = src[0]; d1 = src[1]; d2 = src[2]; d3 = src[3];
    }
    const int p = ly * 22 + lx;
    const int sw = (p >> 1) & 3;
    char* base = vs + ((p << 2) << 4);
    *(uint4*)(base + ((0 ^ sw) << 4)) = d0;
    *(uint4*)(base + ((1 ^ sw) << 4)) = d1;
    *(uint4*)(base + ((2 ^ sw) << 4)) = d2;
    *(uint4*)(base + ((3 ^ sw) << 4)) = d3;
  }
  // ---- stage weights [tap][c] fp32 + bias
  for (int e = tid; e < K * K * 32; e += 256)
    wlds[e] = wp[(e >> 5) * OC + ocbase + (e & 31)];
  if (tid < 32) blds[tid] = bp[ocbase + tid];
  __syncthreads();

  // ---- conv: acc[4] = f32x8 chunks, init with bias
  const float4* bl4 = (const float4*)blds;
  f32x8 acc[4];
#pragma unroll
  for (int cc = 0; cc < 4; ++cc) {
    const float4 b0 = bl4[cc * 2], b1 = bl4[cc * 2 + 1];
    acc[cc][0] = b0.x; acc[cc][1] = b0.y; acc[cc][2] = b0.z; acc[cc][3] = b0.w;
    acc[cc][4] = b1.x; acc[cc][5] = b1.y; acc[cc][6] = b1.z; acc[cc][7] = b1.w;
  }
  const float4* wlds4 = (const float4*)wlds;
#pragma unroll 1
  for (int ky = 0; ky < K; ++ky) {
#pragma unroll
    for (int kx = 0; kx < K; ++kx) {
      const int p = (py + ky) * 22 + (px + kx);
      const int tap = ky * K + kx;
      const int sw = (p >> 1) & 3;
      const char* base = vs + ((p << 2) << 4);
#pragma unroll
      for (int cc = 0; cc < 4; ++cc) {
        const uint4 vv = *(const uint4*)(base + ((cc ^ sw) << 4));
        const f32x8 vf = unpack8(vv);
        const float4 w0 = wlds4[tap * 8 + cc * 2];
        const float4 w1 = wlds4[tap * 8 + cc * 2 + 1];
        acc[cc][0] += vf[0] * w0.x; acc[cc][1] += vf[1] * w0.y;
        acc[cc][2] += vf[2] * w0.z; acc[cc][3] += vf[3] * w0.w;
        acc[cc][4] += vf[4] * w1.x; acc[cc][5] += vf[5] * w1.y;
        acc[cc][6] += vf[6] * w1.z; acc[cc][7] += vf[7] * w1.w;
      }
    }
  }

  // ---- combine with q and kv, store mid token-major
  const int n = (ty0 + py) * 128 + (tx0 + px);
  const size_t off = ((size_t)b * 16384 + n) * 256 + h * 32;
  const uint4* qsrc = (const uint4*)(qT + off);
  f32x8 qv[4];
  float ss = 0.f;
#pragma unroll
  for (int cc = 0; cc < 4; ++cc) {
    qv[cc] = unpack8(qsrc[cc]);
#pragma unroll
    for (int i = 0; i < 8; ++i) ss += qv[cc][i] * qv[cc][i];
  }
  const float qinv = rsqrtf(ss);
  const float4* kvp = (const float4*)(kvbuf + ((size_t)b * 8 + h) * 32);
  uint4* mdst = (uint4*)(mid + off);
#pragma unroll
  for (int cc = 0; cc < 4; ++cc) {
    const float4 ka = kvp[cc * 2], kb = kvp[cc * 2 + 1];
    float o[8];
    o[0] = SCALE_ * qv[cc][0] * qinv * ka.x + qv[cc][0] * acc[cc][0];
    o[1] = SCALE_ * qv[cc][1] * qinv * ka.y + qv[cc][1] * acc[cc][1];
    o[2] = SCALE_ * qv[cc][2] * qinv * ka.z + qv[cc][2] * acc[cc][2];
    o[3] = SCALE_ * qv[cc][3] * qinv * ka.w + qv[cc][3] * acc[cc][3];
    o[4] = SCALE_ * qv[cc][4] * qinv * kb.x + qv[cc][4] * acc[cc][4];
    o[5] = SCALE_ * qv[cc][5] * qinv * kb.y + qv[cc][5] * acc[cc][5];
    o[6] = SCALE_ * qv[cc][6] * qinv * kb.z + qv[cc][6] * acc[cc][6];
    o[7] = SCALE_ * qv[cc][7] * qinv * kb.w + qv[cc][7] * acc[cc][7];
    mdst[cc] = pack8(o[0], o[1], o[2], o[3], o[4], o[5], o[6], o[7]);
  }
}

// --------------------------------------------------------------- K3: proj MFMA
// grid (2, 1024), block 256. M=j, N=token, K=256, BK=32. Both via gload16.
__global__ __launch_bounds__(256) void proj_mfma(
    const bf16* __restrict__ mid, const bf16* __restrict__ wpT,
    const float* __restrict__ bproj, float* __restrict__ out) {
  __shared__ __align__(16) char As[8192];
  __shared__ __align__(16) char Bs[8192];
  const int tid = threadIdx.x;
  const int l = tid & 63, w = tid >> 6;
  const int wr = w >> 1, wc = w & 1;  // wr: j half, wc: token half
  const int j0 = blockIdx.x << 7;
  const int tk0 = blockIdx.y << 7;

  f32x4 acc[4][4];
#pragma unroll
  for (int m = 0; m < 4; ++m)
#pragma unroll
    for (int t = 0; t < 4; ++t) acc[m][t] = (f32x4){0.f, 0.f, 0.f, 0.f};

  const int row0 = w * 16 + (l >> 2), row1 = row0 + 64;
  const int sl = l & 3;
  const bf16* asrc0 = wpT + (size_t)(j0 + row0) * 256 + ((sl ^ (row0 & 3)) << 3);
  const bf16* asrc1 = wpT + (size_t)(j0 + row1) * 256 + ((sl ^ (row1 & 3)) << 3);
  const bf16* bsrc0 = mid + (size_t)(tk0 + row0) * 256 + ((sl ^ (row0 & 3)) << 3);
  const bf16* bsrc1 = mid + (size_t)(tk0 + row1) * 256 + ((sl ^ (row1 & 3)) << 3);
  char* adst0 = As + w * 1024;
  char* adst1 = As + 4096 + w * 1024;
  char* bdst0 = Bs + w * 1024;
  char* bdst1 = Bs + 4096 + w * 1024;

  const int fr = l & 15;
  const int fs = ((l >> 4) ^ (l & 3)) << 4;

  for (int k0 = 0; k0 < 256; k0 += 32) {
    __syncthreads();
    gload16(asrc0 + k0, adst0);
    gload16(asrc1 + k0, adst1);
    gload16(bsrc0 + k0, bdst0);
    gload16(bsrc1 + k0, bdst1);
    __syncthreads();
    u16x8 af[4], bfv[4];
#pragma unroll
    for (int m = 0; m < 4; ++m)
      af[m] = *(const u16x8*)(As + (wr * 64 + m * 16 + fr) * 64 + fs);
#pragma unroll
    for (int t = 0; t < 4; ++t)
      bfv[t] = *(const u16x8*)(Bs + (wc * 64 + t * 16 + fr) * 64 + fs);
#pragma unroll
    for (int m = 0; m < 4; ++m)
#pragma unroll
      for (int t = 0; t < 4; ++t)
        acc[m][t] = mfma16(af[m], bfv[t], acc[m][t]);
  }

  const int fq = l >> 4;
#pragma unroll
  for (int m = 0; m < 4; ++m) {
    const int j = j0 + wr * 64 + m * 16 + fq * 4;
    const float4 bias = *(const float4*)&bproj[j];
#pragma unroll
    for (int t = 0; t < 4; ++t) {
      const int token = tk0 + wc * 64 + t * 16 + fr;
      float4 r;
      r.x = acc[m][t][0] + bias.x;
      r.y = acc[m][t][1] + bias.y;
      r.z = acc[m][t][2] + bias.z;
      r.w = acc[m][t][3] + bias.w;
      *(float4*)&out[(size_t)token * 256 + j] = r;
    }
  }
}

// ------------------------------------------------------------------- launcher
extern "C" void kernel_launch(void* const* d_in, const int* in_sizes, int n_in,
                              void* d_out, int out_size, void* d_ws,
                              size_t ws_size, hipStream_t stream) {
  const float* x     = (const float*)d_in[0];
  const float* wqkv  = (const float*)d_in[1];
  const float* wproj = (const float*)d_in[2];
  const float* bproj = (const float*)d_in[3];
  const float* w3 = (const float*)d_in[4];
  const float* b3 = (const float*)d_in[5];
  const float* w5 = (const float*)d_in[6];
  const float* b5 = (const float*)d_in[7];
  const float* w7 = (const float*)d_in[8];
  const float* b7 = (const float*)d_in[9];
  float* out = (float*)d_out;

  const size_t PLANE = (size_t)8 * 16384 * 256;  // 33,554,432 bf16
  bf16* qT  = (bf16*)d_ws;            // 64 MiB
  bf16* vT  = qT + PLANE;             // 64 MiB
  bf16* kT  = vT + PLANE;             // 64 MiB; mid aliases (k dead after kv)
  bf16* mid = kT;
  float* kv = (float*)(kT + PLANE);   // 8 KB
  bf16* wqkvT  = (bf16*)(kv + 2048);  // 384 KB
  bf16* wprojT = wqkvT + 768 * 256;   // 128 KB

  hipMemsetAsync(kv, 0, 2048 * sizeof(float), stream);
  prep_weights<<<dim3(768), 256, 0, stream>>>(wqkv, wproj, wqkvT, wprojT);
  qkv_mfma<<<dim3(6, 1024), 256, 0, stream>>>(x, wqkvT, qT, kT, vT);
  kv_reduce<<<dim3(16, 64), 256, 0, stream>>>(kT, vT, kv);
  crpe_conv<3><<<dim3(2, 64, 8), 256, 0, stream>>>(qT, vT, kv, w3, b3, 64, 0, mid);
  crpe_conv<5><<<dim3(3, 64, 8), 256, 0, stream>>>(qT, vT, kv, w5, b5, 96, 2, mid);
  crpe_conv<7><<<dim3(3, 64, 8), 256, 0, stream>>>(qT, vT, kv, w7, b7, 96, 5, mid);
  proj_mfma<<<dim3(2, 1024), 256, 0, stream>>>(mid, wprojT, bproj, out);
}

// Round 4
// 420.590 us; speedup vs baseline: 3.0920x; 1.0720x over previous
//
#include <hip/hip_runtime.h>
#include <hip/hip_bf16.h>

// HydraAttention  B=8 N=16384 C=256 NH=8 CH=32 H=W=128
// All intermediates TOKEN-major: q,k,v,mid = [b][n][C] bf16 (64B head slices).
// K0  prep: wqkvT[j][k], wprojT[j][k] bf16 transposed weights
// K1  qkv_mfma: A=wqkvT(j rows) x B=x(tokens) -> q,k,v token-major
//      double-buffered LDS, prefetch-next-K-step, XCD-chunked block swizzle
// K1b kv_reduce: kv[b,h,c] = sum_n kn*v   (token-major 64B slice reads)
// K2  crpe<K>: stage 32ch v tile+halo in LDS (swizzled), conv+combine -> mid
// K3  proj_mfma: out = mid @ w_proj + b_proj (fp32 row-major), same dbuf

typedef __hip_bfloat16 bf16;
typedef __bf16 bf16x8 __attribute__((ext_vector_type(8)));
typedef unsigned short u16x8 __attribute__((ext_vector_type(8)));
typedef float f32x4 __attribute__((ext_vector_type(4)));
typedef float f32x8 __attribute__((ext_vector_type(8)));

#define SCALE_ 0.17677669529663687f

__device__ __forceinline__ unsigned short f2b(float f) {
  __hip_bfloat16 h = __float2bfloat16(f);
  return __builtin_bit_cast(unsigned short, h);
}
__device__ __forceinline__ float blo(unsigned u) {
  return __builtin_bit_cast(float, u << 16);
}
__device__ __forceinline__ float bhi(unsigned u) {
  return __builtin_bit_cast(float, u & 0xffff0000u);
}
__device__ __forceinline__ f32x8 unpack8(uint4 u) {
  f32x8 r;
  r[0] = blo(u.x); r[1] = bhi(u.x); r[2] = blo(u.y); r[3] = bhi(u.y);
  r[4] = blo(u.z); r[5] = bhi(u.z); r[6] = blo(u.w); r[7] = bhi(u.w);
  return r;
}
__device__ __forceinline__ uint4 pack8(float a0, float a1, float a2, float a3,
                                       float a4, float a5, float a6, float a7) {
  uint4 s;
  s.x = (unsigned)f2b(a0) | ((unsigned)f2b(a1) << 16);
  s.y = (unsigned)f2b(a2) | ((unsigned)f2b(a3) << 16);
  s.z = (unsigned)f2b(a4) | ((unsigned)f2b(a5) << 16);
  s.w = (unsigned)f2b(a6) | ((unsigned)f2b(a7) << 16);
  return s;
}
__device__ __forceinline__ void gload16(const void* g, void* l) {
  __builtin_amdgcn_global_load_lds(
      (const __attribute__((address_space(1))) unsigned int*)g,
      (__attribute__((address_space(3))) unsigned int*)l, 16, 0, 0);
}
__device__ __forceinline__ f32x4 mfma16(u16x8 a, u16x8 b, f32x4 c) {
  return __builtin_amdgcn_mfma_f32_16x16x32_bf16(
      __builtin_bit_cast(bf16x8, a), __builtin_bit_cast(bf16x8, b), c, 0, 0, 0);
}

// ------------------------------------------------------------- weight prep
__global__ __launch_bounds__(256) void prep_weights(
    const float* __restrict__ wqkv, const float* __restrict__ wproj,
    bf16* __restrict__ wqkvT, bf16* __restrict__ wprojT) {
  const int idx = blockIdx.x * 256 + threadIdx.x;
  if (idx < 768 * 256) {
    const int j = idx >> 8, k = idx & 255;
    wqkvT[idx] = __float2bfloat16(wqkv[k * 768 + j]);
  }
  if (idx < 256 * 256) {
    const int j = idx >> 8, k = idx & 255;
    wprojT[idx] = __float2bfloat16(wproj[k * 256 + j]);
  }
}

// --------------------------------------------------------------- K1: qkv MFMA
// grid (6, 1024), block 256 (4 waves). M=j(128 rows), N=tokens(128), BK=32.
// Double-buffered LDS (2x8 KiB per operand). XCD-chunked swizzle: all 6
// j-tiles of one token tile run on the same XCD (share its L2 x-tile).
__global__ __launch_bounds__(256) void qkv_mfma(
    const float* __restrict__ x, const bf16* __restrict__ wT,
    bf16* __restrict__ qO, bf16* __restrict__ kO, bf16* __restrict__ vO) {
  __shared__ __align__(16) char As[16384];  // 2 buffers x 8192
  __shared__ __align__(16) char Bs[16384];
  const int tid = threadIdx.x;
  const int l = tid & 63, w = tid >> 6;
  const int wr = w >> 1, wc = w & 1;  // wr: j half, wc: token half

  // bijective XCD-chunked remap (6144 blocks, 6144%8==0)
  const int lin = blockIdx.y * 6 + blockIdx.x;
  const int xcd = lin & 7, qq = lin >> 3;      // qq in [0,768)
  const int jt = qq % 6;                        // j tile
  const int ttile = xcd * 128 + qq / 6;         // token tile
  const int j0 = jt << 7;
  const int t0 = ttile << 7;

  f32x4 acc[4][4];
#pragma unroll
  for (int m = 0; m < 4; ++m)
#pragma unroll
    for (int t = 0; t < 4; ++t) acc[m][t] = (f32x4){0.f, 0.f, 0.f, 0.f};

  // A staging (gload16): wave w shot rows w*16.. and +64, source pre-swizzled
  const int arow0 = w * 16 + (l >> 2), arow1 = arow0 + 64;
  const int asl = l & 3;
  const bf16* asrc0 = wT + (size_t)(j0 + arow0) * 256 + ((asl ^ (arow0 & 3)) << 3);
  const bf16* asrc1 = wT + (size_t)(j0 + arow1) * 256 + ((asl ^ (arow1 & 3)) << 3);
  const int ad0 = w * 1024;          // dst byte offset within buffer
  const int ad1 = 4096 + w * 1024;

  // B reg-staging: thread covers (token row = tid>>1, k-half = tid&1)
  const int brow = tid >> 1, bkh = tid & 1;
  const float* xp = x + (size_t)(t0 + brow) * 256 + bkh * 16;
  const int bw0 = brow * 64 + (((bkh << 1) ^ (brow & 3)) << 4);
  const int bw1 = brow * 64 + ((((bkh << 1) | 1) ^ (brow & 3)) << 4);

  const int fr = l & 15;
  const int fs = ((l >> 4) ^ (l & 3)) << 4;  // swizzled fragment slot byte

  // ---- prologue: stage K-step 0 into buffer 0
  {
    const float4 xa0 = *(const float4*)(xp);
    const float4 xa1 = *(const float4*)(xp + 4);
    const float4 xa2 = *(const float4*)(xp + 8);
    const float4 xa3 = *(const float4*)(xp + 12);
    gload16(asrc0, As + ad0);
    gload16(asrc1, As + ad1);
    u16x8 p0, p1;
    p0[0] = f2b(xa0.x); p0[1] = f2b(xa0.y); p0[2] = f2b(xa0.z); p0[3] = f2b(xa0.w);
    p0[4] = f2b(xa1.x); p0[5] = f2b(xa1.y); p0[6] = f2b(xa1.z); p0[7] = f2b(xa1.w);
    p1[0] = f2b(xa2.x); p1[1] = f2b(xa2.y); p1[2] = f2b(xa2.z); p1[3] = f2b(xa2.w);
    p1[4] = f2b(xa3.x); p1[5] = f2b(xa3.y); p1[6] = f2b(xa3.z); p1[7] = f2b(xa3.w);
    *(u16x8*)(Bs + bw0) = p0;
    *(u16x8*)(Bs + bw1) = p1;
  }
  __syncthreads();

  int cur = 0;
  for (int t = 0; t < 8; ++t) {
    const int kn = (t + 1) << 5;  // next K-step base
    const int nxt = (cur ^ 1) << 13;
    float4 xa0, xa1, xa2, xa3;
    if (t < 7) {  // issue next-step loads early (hide under MFMA)
      xa0 = *(const float4*)(xp + kn);
      xa1 = *(const float4*)(xp + kn + 4);
      xa2 = *(const float4*)(xp + kn + 8);
      xa3 = *(const float4*)(xp + kn + 12);
      gload16(asrc0 + kn, As + nxt + ad0);
      gload16(asrc1 + kn, As + nxt + ad1);
    }
    const char* Ac = As + (cur << 13);
    const char* Bc = Bs + (cur << 13);
    u16x8 af[4], bfv[4];
#pragma unroll
    for (int m = 0; m < 4; ++m)
      af[m] = *(const u16x8*)(Ac + (wr * 64 + m * 16 + fr) * 64 + fs);
#pragma unroll
    for (int tt = 0; tt < 4; ++tt)
      bfv[tt] = *(const u16x8*)(Bc + (wc * 64 + tt * 16 + fr) * 64 + fs);
#pragma unroll
    for (int m = 0; m < 4; ++m)
#pragma unroll
      for (int tt = 0; tt < 4; ++tt)
        acc[m][tt] = mfma16(af[m], bfv[tt], acc[m][tt]);
    if (t < 7) {  // convert + LDS-write after the MFMA cluster
      u16x8 p0, p1;
      p0[0] = f2b(xa0.x); p0[1] = f2b(xa0.y); p0[2] = f2b(xa0.z); p0[3] = f2b(xa0.w);
      p0[4] = f2b(xa1.x); p0[5] = f2b(xa1.y); p0[6] = f2b(xa1.z); p0[7] = f2b(xa1.w);
      p1[0] = f2b(xa2.x); p1[1] = f2b(xa2.y); p1[2] = f2b(xa2.z); p1[3] = f2b(xa2.w);
      p1[4] = f2b(xa3.x); p1[5] = f2b(xa3.y); p1[6] = f2b(xa3.z); p1[7] = f2b(xa3.w);
      *(u16x8*)(Bs + nxt + bw0) = p0;
      *(u16x8*)(Bs + nxt + bw1) = p1;
    }
    __syncthreads();
    cur ^= 1;
  }

  const int region = j0 >> 8;  // 0:q 1:k 2:v
  bf16* outp = (region == 0) ? qO : ((region == 1) ? kO : vO);
  const int b = t0 >> 14;
  const int n0 = (t0 & 16383) + wc * 64;
  const int fq = l >> 4;
  const int jl = (j0 & 255) + wr * 64;
#pragma unroll
  for (int m = 0; m < 4; ++m) {
    const int j = jl + m * 16 + fq * 4;
#pragma unroll
    for (int t = 0; t < 4; ++t) {
      const int n = n0 + t * 16 + fr;
      uint2 pk;
      pk.x = (unsigned)f2b(acc[m][t][0]) | ((unsigned)f2b(acc[m][t][1]) << 16);
      pk.y = (unsigned)f2b(acc[m][t][2]) | ((unsigned)f2b(acc[m][t][3]) << 16);
      *(uint2*)&outp[((size_t)b * 16384 + n) * 256 + j] = pk;
    }
  }
}

// ------------------------------------------------------------ K1b: kv reduce
// grid (16, 64), block 256. bh = blockIdx.y. Token-major 64B slice reads.
__global__ __launch_bounds__(256) void kv_reduce(
    const bf16* __restrict__ kT, const bf16* __restrict__ vT,
    float* __restrict__ kv) {
  const int tid = threadIdx.x;
  const int bh = blockIdx.y;
  const int b = bh >> 3, h = bh & 7;
  f32x8 part[4];
#pragma unroll
  for (int cc = 0; cc < 4; ++cc) part[cc] = (f32x8)0.f;

  for (int it = 0; it < 4; ++it) {
    const int n = blockIdx.x * 1024 + it * 256 + tid;
    const size_t off = ((size_t)b * 16384 + n) * 256 + h * 32;
    const uint4* kp = (const uint4*)(kT + off);
    const uint4* vp = (const uint4*)(vT + off);
    f32x8 kf[4];
    float ss = 0.f;
#pragma unroll
    for (int cc = 0; cc < 4; ++cc) {
      kf[cc] = unpack8(kp[cc]);
#pragma unroll
      for (int i = 0; i < 8; ++i) ss += kf[cc][i] * kf[cc][i];
    }
    const float inv = rsqrtf(ss);
#pragma unroll
    for (int cc = 0; cc < 4; ++cc) {
      f32x8 vf = unpack8(vp[cc]);
#pragma unroll
      for (int i = 0; i < 8; ++i) part[cc][i] += kf[cc][i] * inv * vf[i];
    }
  }
#pragma unroll
  for (int cc = 0; cc < 4; ++cc)
#pragma unroll
    for (int i = 0; i < 8; ++i) {
      float p = part[cc][i];
#pragma unroll
      for (int off = 32; off >= 1; off >>= 1) p += __shfl_xor(p, off);
      part[cc][i] = p;
    }
  if ((tid & 63) == 0) {
#pragma unroll
    for (int cc = 0; cc < 4; ++cc)
#pragma unroll
      for (int i = 0; i < 8; ++i)
        atomicAdd(&kv[bh * 32 + cc * 8 + i], part[cc][i]);
  }
}

// ------------------------------------------------- K2: crpe conv + combine
// template<K>. grid (HEADS, 64, 8): x=head-in-group, y=tile(8x8), z=b.
// Block = 256 threads = 16x16 pixels. LDS: v tile+halo, 32ch bf16 per pixel
// (4x 16B slots, swizzle slot = 4p + (j ^ ((p>>1)&3))), + weights fp32.
template <int K>
__global__ __launch_bounds__(256) void crpe_conv(
    const bf16* __restrict__ qT, const bf16* __restrict__ vT,
    const float* __restrict__ kvbuf, const float* __restrict__ wp,
    const float* __restrict__ bp, int OC, int hbase,
    bf16* __restrict__ mid) {
  constexpr int R = K / 2;
  constexpr int S = 16 + 2 * R;
  constexpr int NSLOT = 4 * ((S - 1) * 23 + 1);
  __shared__ __align__(16) char vs[NSLOT * 16];
  __shared__ float wlds[K * K * 32];
  __shared__ float blds[32];

  const int tid = threadIdx.x;
  const int hg = blockIdx.x;
  const int h = hbase + hg;
  const int tile = blockIdx.y;
  const int b = blockIdx.z;
  const int tx0 = (tile & 7) * 16, ty0 = (tile >> 3) * 16;
  const int px = tid & 15, py = tid >> 4;
  const int ocbase = hg * 32;

  // ---- stage v tile + halo (32 ch/pixel, 64B) with slot swizzle
  for (int e = tid; e < S * S; e += 256) {
    const int ly = e / S, lx = e - ly * S;
    const int gy = ty0 - R + ly, gx = tx0 - R + lx;
    uint4 d0 = {0, 0, 0, 0}, d1 = {0, 0, 0, 0}, d2 = {0, 0, 0, 0},
          d3 = {0, 0, 0, 0};
    if (gy >= 0 && gy < 128 && gx >= 0 && gx < 128) {
      const uint4* src = (const uint4*)(vT +
          ((size_t)b * 16384 + gy * 128 + gx) * 256 + h * 32);
      d0 = src[0]; d1 = src[1]; d2 = src[2]; d3 = src[3];
    }
    const int p = ly * 22 + lx;
    const int sw = (p >> 1) & 3;
    char* base = vs + ((p << 2) << 4);
    *(uint4*)(base + ((0 ^ sw) << 4)) = d0;
    *(uint4*)(base + ((1 ^ sw) << 4)) = d1;
    *(uint4*)(base + ((2 ^ sw) << 4)) = d2;
    *(uint4*)(base + ((3 ^ sw) << 4)) = d3;
  }
  // ---- stage weights [tap][c] fp32 + bias
  for (int e = tid; e < K * K * 32; e += 256)
    wlds[e] = wp[(e >> 5) * OC + ocbase + (e & 31)];
  if (tid < 32) blds[tid] = bp[ocbase + tid];
  __syncthreads();

  // ---- conv: acc[4] = f32x8 chunks, init with bias
  const float4* bl4 = (const float4*)blds;
  f32x8 acc[4];
#pragma unroll
  for (int cc = 0; cc < 4; ++cc) {
    const float4 b0 = bl4[cc * 2], b1 = bl4[cc * 2 + 1];
    acc[cc][0] = b0.x; acc[cc][1] = b0.y; acc[cc][2] = b0.z; acc[cc][3] = b0.w;
    acc[cc][4] = b1.x; acc[cc][5] = b1.y; acc[cc][6] = b1.z; acc[cc][7] = b1.w;
  }
  const float4* wlds4 = (const float4*)wlds;
#pragma unroll 1
  for (int ky = 0; ky < K; ++ky) {
#pragma unroll
    for (int kx = 0; kx < K; ++kx) {
      const int p = (py + ky) * 22 + (px + kx);
      const int tap = ky * K + kx;
      const int sw = (p >> 1) & 3;
      const char* base = vs + ((p << 2) << 4);
#pragma unroll
      for (int cc = 0; cc < 4; ++cc) {
        const uint4 vv = *(const uint4*)(base + ((cc ^ sw) << 4));
        const f32x8 vf = unpack8(vv);
        const float4 w0 = wlds4[tap * 8 + cc * 2];
        const float4 w1 = wlds4[tap * 8 + cc * 2 + 1];
        acc[cc][0] += vf[0] * w0.x; acc[cc][1] += vf[1] * w0.y;
        acc[cc][2] += vf[2] * w0.z; acc[cc][3] += vf[3] * w0.w;
        acc[cc][4] += vf[4] * w1.x; acc[cc][5] += vf[5] * w1.y;
        acc[cc][6] += vf[6] * w1.z; acc[cc][7] += vf[7] * w1.w;
      }
    }
  }

  // ---- combine with q and kv, store mid token-major
  const int n = (ty0 + py) * 128 + (tx0 + px);
  const size_t off = ((size_t)b * 16384 + n) * 256 + h * 32;
  const uint4* qsrc = (const uint4*)(qT + off);
  f32x8 qv[4];
  float ss = 0.f;
#pragma unroll
  for (int cc = 0; cc < 4; ++cc) {
    qv[cc] = unpack8(qsrc[cc]);
#pragma unroll
    for (int i = 0; i < 8; ++i) ss += qv[cc][i] * qv[cc][i];
  }
  const float qinv = rsqrtf(ss);
  const float4* kvp = (const float4*)(kvbuf + ((size_t)b * 8 + h) * 32);
  uint4* mdst = (uint4*)(mid + off);
#pragma unroll
  for (int cc = 0; cc < 4; ++cc) {
    const float4 ka = kvp[cc * 2], kb = kvp[cc * 2 + 1];
    float o[8];
    o[0] = SCALE_ * qv[cc][0] * qinv * ka.x + qv[cc][0] * acc[cc][0];
    o[1] = SCALE_ * qv[cc][1] * qinv * ka.y + qv[cc][1] * acc[cc][1];
    o[2] = SCALE_ * qv[cc][2] * qinv * ka.z + qv[cc][2] * acc[cc][2];
    o[3] = SCALE_ * qv[cc][3] * qinv * ka.w + qv[cc][3] * acc[cc][3];
    o[4] = SCALE_ * qv[cc][4] * qinv * kb.x + qv[cc][4] * acc[cc][4];
    o[5] = SCALE_ * qv[cc][5] * qinv * kb.y + qv[cc][5] * acc[cc][5];
    o[6] = SCALE_ * qv[cc][6] * qinv * kb.z + qv[cc][6] * acc[cc][6];
    o[7] = SCALE_ * qv[cc][7] * qinv * kb.w + qv[cc][7] * acc[cc][7];
    mdst[cc] = pack8(o[0], o[1], o[2], o[3], o[4], o[5], o[6], o[7]);
  }
}

// --------------------------------------------------------------- K3: proj MFMA
// grid (2, 1024), block 256. M=j, N=token, K=256, BK=32. All gload16,
// double-buffered, XCD-chunked swizzle (2048 blocks, %8==0).
__global__ __launch_bounds__(256) void proj_mfma(
    const bf16* __restrict__ mid, const bf16* __restrict__ wpT,
    const float* __restrict__ bproj, float* __restrict__ out) {
  __shared__ __align__(16) char As[16384];
  __shared__ __align__(16) char Bs[16384];
  const int tid = threadIdx.x;
  const int l = tid & 63, w = tid >> 6;
  const int wr = w >> 1, wc = w & 1;  // wr: j half, wc: token half

  const int lin = blockIdx.y * 2 + blockIdx.x;
  const int xcd = lin & 7, qq = lin >> 3;    // qq in [0,256)
  const int jt = qq & 1;
  const int ttile = xcd * 128 + (qq >> 1);
  const int j0 = jt << 7;
  const int tk0 = ttile << 7;

  f32x4 acc[4][4];
#pragma unroll
  for (int m = 0; m < 4; ++m)
#pragma unroll
    for (int t = 0; t < 4; ++t) acc[m][t] = (f32x4){0.f, 0.f, 0.f, 0.f};

  const int row0 = w * 16 + (l >> 2), row1 = row0 + 64;
  const int sl = l & 3;
  const bf16* asrc0 = wpT + (size_t)(j0 + row0) * 256 + ((sl ^ (row0 & 3)) << 3);
  const bf16* asrc1 = wpT + (size_t)(j0 + row1) * 256 + ((sl ^ (row1 & 3)) << 3);
  const bf16* bsrc0 = mid + (size_t)(tk0 + row0) * 256 + ((sl ^ (row0 & 3)) << 3);
  const bf16* bsrc1 = mid + (size_t)(tk0 + row1) * 256 + ((sl ^ (row1 & 3)) << 3);
  const int d0 = w * 1024;
  const int d1 = 4096 + w * 1024;

  const int fr = l & 15;
  const int fs = ((l >> 4) ^ (l & 3)) << 4;

  // prologue: stage K-step 0 into buffer 0
  gload16(asrc0, As + d0);
  gload16(asrc1, As + d1);
  gload16(bsrc0, Bs + d0);
  gload16(bsrc1, Bs + d1);
  __syncthreads();

  int cur = 0;
  for (int t = 0; t < 8; ++t) {
    const int kn = (t + 1) << 5;
    const int nxt = (cur ^ 1) << 13;
    if (t < 7) {
      gload16(asrc0 + kn, As + nxt + d0);
      gload16(asrc1 + kn, As + nxt + d1);
      gload16(bsrc0 + kn, Bs + nxt + d0);
      gload16(bsrc1 + kn, Bs + nxt + d1);
    }
    const char* Ac = As + (cur << 13);
    const char* Bc = Bs + (cur << 13);
    u16x8 af[4], bfv[4];
#pragma unroll
    for (int m = 0; m < 4; ++m)
      af[m] = *(const u16x8*)(Ac + (wr * 64 + m * 16 + fr) * 64 + fs);
#pragma unroll
    for (int tt = 0; tt < 4; ++tt)
      bfv[tt] = *(const u16x8*)(Bc + (wc * 64 + tt * 16 + fr) * 64 + fs);
#pragma unroll
    for (int m = 0; m < 4; ++m)
#pragma unroll
      for (int tt = 0; tt < 4; ++tt)
        acc[m][tt] = mfma16(af[m], bfv[tt], acc[m][tt]);
    __syncthreads();
    cur ^= 1;
  }

  const int fq = l >> 4;
#pragma unroll
  for (int m = 0; m < 4; ++m) {
    const int j = j0 + wr * 64 + m * 16 + fq * 4;
    const float4 bias = *(const float4*)&bproj[j];
#pragma unroll
    for (int t = 0; t < 4; ++t) {
      const int token = tk0 + wc * 64 + t * 16 + fr;
      float4 r;
      r.x = acc[m][t][0] + bias.x;
      r.y = acc[m][t][1] + bias.y;
      r.z = acc[m][t][2] + bias.z;
      r.w = acc[m][t][3] + bias.w;
      *(float4*)&out[(size_t)token * 256 + j] = r;
    }
  }
}

// ------------------------------------------------------------------- launcher
extern "C" void kernel_launch(void* const* d_in, const int* in_sizes, int n_in,
                              void* d_out, int out_size, void* d_ws,
                              size_t ws_size, hipStream_t stream) {
  const float* x     = (const float*)d_in[0];
  const float* wqkv  = (const float*)d_in[1];
  const float* wproj = (const float*)d_in[2];
  const float* bproj = (const float*)d_in[3];
  const float* w3 = (const float*)d_in[4];
  const float* b3 = (const float*)d_in[5];
  const float* w5 = (const float*)d_in[6];
  const float* b5 = (const float*)d_in[7];
  const float* w7 = (const float*)d_in[8];
  const float* b7 = (const float*)d_in[9];
  float* out = (float*)d_out;

  const size_t PLANE = (size_t)8 * 16384 * 256;  // 33,554,432 bf16
  bf16* qT  = (bf16*)d_ws;            // 64 MiB
  bf16* vT  = qT + PLANE;             // 64 MiB
  bf16* kT  = vT + PLANE;             // 64 MiB; mid aliases (k dead after kv)
  bf16* mid = kT;
  float* kv = (float*)(kT + PLANE);   // 8 KB
  bf16* wqkvT  = (bf16*)(kv + 2048);  // 384 KB
  bf16* wprojT = wqkvT + 768 * 256;   // 128 KB

  hipMemsetAsync(kv, 0, 2048 * sizeof(float), stream);
  prep_weights<<<dim3(768), 256, 0, stream>>>(wqkv, wproj, wqkvT, wprojT);
  qkv_mfma<<<dim3(6, 1024), 256, 0, stream>>>(x, wqkvT, qT, kT, vT);
  kv_reduce<<<dim3(16, 64), 256, 0, stream>>>(kT, vT, kv);
  crpe_conv<3><<<dim3(2, 64, 8), 256, 0, stream>>>(qT, vT, kv, w3, b3, 64, 0, mid);
  crpe_conv<5><<<dim3(3, 64, 8), 256, 0, stream>>>(qT, vT, kv, w5, b5, 96, 2, mid);
  crpe_conv<7><<<dim3(3, 64, 8), 256, 0, stream>>>(qT, vT, kv, w7, b7, 96, 5, mid);
  proj_mfma<<<dim3(2, 1024), 256, 0, stream>>>(mid, wprojT, bproj, out);
}

// Round 5
// 344.833 us; speedup vs baseline: 3.7713x; 1.2197x over previous
//
#include <hip/hip_runtime.h>
#include <hip/hip_bf16.h>

// HydraAttention  B=8 N=16384 C=256 NH=8 CH=32 H=W=128
// All intermediates TOKEN-major: q,k,v,mid = [b][n][C] bf16 (64B head slices).
// K0  prep: wqkvT[j][k], wprojT[j][k] bf16 transposed weights
// K1  qkv_mfma: A=wqkvT(j rows) x B=x(tokens), dbuf LDS, XCD swizzle,
//      LDS-transpose epilogue -> coalesced 256B-run stores
// K1b kv_reduce: full-row coalesced reads, 4-lane shfl k-norm, LDS reduce
// K2  crpe<K>: stage 32ch v tile+halo in LDS (swizzled), conv+combine -> mid
// K3  proj_mfma: same structure, fp32 LDS-transpose epilogue (2 chunks)

typedef __hip_bfloat16 bf16;
typedef __bf16 bf16x8 __attribute__((ext_vector_type(8)));
typedef unsigned short u16x8 __attribute__((ext_vector_type(8)));
typedef float f32x4 __attribute__((ext_vector_type(4)));
typedef float f32x8 __attribute__((ext_vector_type(8)));

#define SCALE_ 0.17677669529663687f

__device__ __forceinline__ unsigned short f2b(float f) {
  __hip_bfloat16 h = __float2bfloat16(f);
  return __builtin_bit_cast(unsigned short, h);
}
__device__ __forceinline__ float blo(unsigned u) {
  return __builtin_bit_cast(float, u << 16);
}
__device__ __forceinline__ float bhi(unsigned u) {
  return __builtin_bit_cast(float, u & 0xffff0000u);
}
__device__ __forceinline__ f32x8 unpack8(uint4 u) {
  f32x8 r;
  r[0] = blo(u.x); r[1] = bhi(u.x); r[2] = blo(u.y); r[3] = bhi(u.y);
  r[4] = blo(u.z); r[5] = bhi(u.z); r[6] = blo(u.w); r[7] = bhi(u.w);
  return r;
}
__device__ __forceinline__ uint4 pack8(float a0, float a1, float a2, float a3,
                                       float a4, float a5, float a6, float a7) {
  uint4 s;
  s.x = (unsigned)f2b(a0) | ((unsigned)f2b(a1) << 16);
  s.y = (unsigned)f2b(a2) | ((unsigned)f2b(a3) << 16);
  s.z = (unsigned)f2b(a4) | ((unsigned)f2b(a5) << 16);
  s.w = (unsigned)f2b(a6) | ((unsigned)f2b(a7) << 16);
  return s;
}
__device__ __forceinline__ void gload16(const void* g, void* l) {
  __builtin_amdgcn_global_load_lds(
      (const __attribute__((address_space(1))) unsigned int*)g,
      (__attribute__((address_space(3))) unsigned int*)l, 16, 0, 0);
}
__device__ __forceinline__ f32x4 mfma16(u16x8 a, u16x8 b, f32x4 c) {
  return __builtin_amdgcn_mfma_f32_16x16x32_bf16(
      __builtin_bit_cast(bf16x8, a), __builtin_bit_cast(bf16x8, b), c, 0, 0, 0);
}

// ------------------------------------------------------------- weight prep
__global__ __launch_bounds__(256) void prep_weights(
    const float* __restrict__ wqkv, const float* __restrict__ wproj,
    bf16* __restrict__ wqkvT, bf16* __restrict__ wprojT) {
  const int idx = blockIdx.x * 256 + threadIdx.x;
  if (idx < 768 * 256) {
    const int j = idx >> 8, k = idx & 255;
    wqkvT[idx] = __float2bfloat16(wqkv[k * 768 + j]);
  }
  if (idx < 256 * 256) {
    const int j = idx >> 8, k = idx & 255;
    wprojT[idx] = __float2bfloat16(wproj[k * 256 + j]);
  }
}

// --------------------------------------------------------------- K1: qkv MFMA
// grid (6, 1024), block 256 (4 waves). M=j(128), N=tokens(128), BK=32, dbuf.
// LDS swizzle: physical 16B slot = logical ^ ((row>>1)&3)  (2 lanes/bank=free).
// Epilogue: acc -> LDS [token][j] (quad-XOR swizzle) -> 256B-run stores.
__global__ __launch_bounds__(256) void qkv_mfma(
    const float* __restrict__ x, const bf16* __restrict__ wT,
    bf16* __restrict__ qO, bf16* __restrict__ kO, bf16* __restrict__ vO) {
  __shared__ __align__(16) char LDSU[32768];
  char* As = LDSU;           // 2 x 8 KiB
  char* Bs = LDSU + 16384;   // 2 x 8 KiB
  const int tid = threadIdx.x;
  const int l = tid & 63, w = tid >> 6;
  const int wr = w >> 1, wc = w & 1;  // wr: j half, wc: token half

  // bijective XCD-chunked remap (6144 blocks, 6144%8==0)
  const int lin = blockIdx.y * 6 + blockIdx.x;
  const int xcd = lin & 7, qq = lin >> 3;
  const int jt = qq % 6;
  const int ttile = xcd * 128 + qq / 6;
  const int j0 = jt << 7;
  const int t0 = ttile << 7;

  f32x4 acc[4][4];
#pragma unroll
  for (int m = 0; m < 4; ++m)
#pragma unroll
    for (int t = 0; t < 4; ++t) acc[m][t] = (f32x4){0.f, 0.f, 0.f, 0.f};

  // A staging (gload16): source pre-swizzled with ((row>>1)&3)
  const int arow0 = w * 16 + (l >> 2), arow1 = arow0 + 64;
  const int asl = l & 3;
  const bf16* asrc0 =
      wT + (size_t)(j0 + arow0) * 256 + ((asl ^ ((arow0 >> 1) & 3)) << 3);
  const bf16* asrc1 =
      wT + (size_t)(j0 + arow1) * 256 + ((asl ^ ((arow1 >> 1) & 3)) << 3);
  const int ad0 = w * 1024;
  const int ad1 = 4096 + w * 1024;

  // B reg-staging: thread covers (token row = tid>>1, k-half = tid&1)
  const int brow = tid >> 1, bkh = tid & 1;
  const float* xp = x + (size_t)(t0 + brow) * 256 + bkh * 16;
  const int bsw = (brow >> 1) & 3;
  const int bw0 = brow * 64 + (((bkh << 1) ^ bsw) << 4);
  const int bw1 = brow * 64 + ((((bkh << 1) | 1) ^ bsw) << 4);

  const int fr = l & 15;
  const int fq = l >> 4;
  const int fs = (fq ^ ((l >> 1) & 3)) << 4;  // slot ^ ((row>>1)&3), row&15=fr

  // ---- prologue: stage K-step 0 into buffer 0
  {
    const float4 xa0 = *(const float4*)(xp);
    const float4 xa1 = *(const float4*)(xp + 4);
    const float4 xa2 = *(const float4*)(xp + 8);
    const float4 xa3 = *(const float4*)(xp + 12);
    gload16(asrc0, As + ad0);
    gload16(asrc1, As + ad1);
    u16x8 p0, p1;
    p0[0] = f2b(xa0.x); p0[1] = f2b(xa0.y); p0[2] = f2b(xa0.z); p0[3] = f2b(xa0.w);
    p0[4] = f2b(xa1.x); p0[5] = f2b(xa1.y); p0[6] = f2b(xa1.z); p0[7] = f2b(xa1.w);
    p1[0] = f2b(xa2.x); p1[1] = f2b(xa2.y); p1[2] = f2b(xa2.z); p1[3] = f2b(xa2.w);
    p1[4] = f2b(xa3.x); p1[5] = f2b(xa3.y); p1[6] = f2b(xa3.z); p1[7] = f2b(xa3.w);
    *(u16x8*)(Bs + bw0) = p0;
    *(u16x8*)(Bs + bw1) = p1;
  }
  __syncthreads();

  int cur = 0;
  for (int t = 0; t < 8; ++t) {
    const int kn = (t + 1) << 5;
    const int nxt = (cur ^ 1) << 13;
    float4 xa0, xa1, xa2, xa3;
    if (t < 7) {
      xa0 = *(const float4*)(xp + kn);
      xa1 = *(const float4*)(xp + kn + 4);
      xa2 = *(const float4*)(xp + kn + 8);
      xa3 = *(const float4*)(xp + kn + 12);
      gload16(asrc0 + kn, As + nxt + ad0);
      gload16(asrc1 + kn, As + nxt + ad1);
    }
    const char* Ac = As + (cur << 13);
    const char* Bc = Bs + (cur << 13);
    u16x8 af[4], bfv[4];
#pragma unroll
    for (int m = 0; m < 4; ++m)
      af[m] = *(const u16x8*)(Ac + (wr * 64 + m * 16 + fr) * 64 + fs);
#pragma unroll
    for (int tt = 0; tt < 4; ++tt)
      bfv[tt] = *(const u16x8*)(Bc + (wc * 64 + tt * 16 + fr) * 64 + fs);
#pragma unroll
    for (int m = 0; m < 4; ++m)
#pragma unroll
      for (int tt = 0; tt < 4; ++tt)
        acc[m][tt] = mfma16(af[m], bfv[tt], acc[m][tt]);
    if (t < 7) {
      u16x8 p0, p1;
      p0[0] = f2b(xa0.x); p0[1] = f2b(xa0.y); p0[2] = f2b(xa0.z); p0[3] = f2b(xa0.w);
      p0[4] = f2b(xa1.x); p0[5] = f2b(xa1.y); p0[6] = f2b(xa1.z); p0[7] = f2b(xa1.w);
      p1[0] = f2b(xa2.x); p1[1] = f2b(xa2.y); p1[2] = f2b(xa2.z); p1[3] = f2b(xa2.w);
      p1[4] = f2b(xa3.x); p1[5] = f2b(xa3.y); p1[6] = f2b(xa3.z); p1[7] = f2b(xa3.w);
      *(u16x8*)(Bs + nxt + bw0) = p0;
      *(u16x8*)(Bs + nxt + bw1) = p1;
    }
    __syncthreads();
    cur ^= 1;
  }

  // ---- epilogue: transpose through LDS, coalesced stores
  // write: [token][j] bf16, 128x256B = 32KB; quad (8B) swizzle p = jq^(tok&15)
#pragma unroll
  for (int m = 0; m < 4; ++m) {
    const int jq = wr * 16 + m * 4 + fq;
#pragma unroll
    for (int t = 0; t < 4; ++t) {
      const int token = wc * 64 + t * 16 + fr;
      const int p = jq ^ (token & 15);
      uint2 pk;
      pk.x = (unsigned)f2b(acc[m][t][0]) | ((unsigned)f2b(acc[m][t][1]) << 16);
      pk.y = (unsigned)f2b(acc[m][t][2]) | ((unsigned)f2b(acc[m][t][3]) << 16);
      *(uint2*)(LDSU + token * 256 + (p << 3)) = pk;
    }
  }
  __syncthreads();

  const int region = j0 >> 8;  // 0:q 1:k 2:v
  bf16* outp = (region == 0) ? qO : ((region == 1) ? kO : vO);
  const int b = t0 >> 14;
  const int n0 = t0 & 16383;
  const int jl = j0 & 255;
  const int seg = tid & 15;
#pragma unroll
  for (int r = 0; r < 8; ++r) {
    const int token = r * 16 + (tid >> 4);
    const int tsw = token & 15;
    const int q0 = (2 * seg) ^ tsw;
    const int q1 = (2 * seg + 1) ^ tsw;
    const uint2 lo = *(const uint2*)(LDSU + token * 256 + (q0 << 3));
    const uint2 hi = *(const uint2*)(LDSU + token * 256 + (q1 << 3));
    uint4 d;
    d.x = lo.x; d.y = lo.y; d.z = hi.x; d.w = hi.y;
    *(uint4*)&outp[((size_t)b * 16384 + n0 + token) * 256 + jl + seg * 8] = d;
  }
}

// ------------------------------------------------------------ K1b: kv reduce
// grid (64, 8), block 256. Full 512B token-row cooperative reads.
// seg=tid&31 -> (h=seg>>2, octet=seg&3); k-norm via 4-lane shfl_xor.
__global__ __launch_bounds__(256) void kv_reduce(
    const bf16* __restrict__ kT, const bf16* __restrict__ vT,
    float* __restrict__ kv) {
  __shared__ float red[256 * 8];
  const int tid = threadIdx.x;
  const int b = blockIdx.y;
  const int seg = tid & 31;
  f32x8 part = (f32x8)0.f;

  for (int r = 0; r < 32; ++r) {
    const int token = blockIdx.x * 256 + r * 8 + (tid >> 5);
    const size_t roff = ((size_t)b * 16384 + token) * 256;
    const uint4 kd = *(const uint4*)(kT + roff + seg * 8);
    const f32x8 kf = unpack8(kd);
    float ss = 0.f;
#pragma unroll
    for (int i = 0; i < 8; ++i) ss += kf[i] * kf[i];
    ss += __shfl_xor(ss, 1);
    ss += __shfl_xor(ss, 2);
    const float inv = rsqrtf(ss);
    const uint4 vd = *(const uint4*)(vT + roff + seg * 8);
    const f32x8 vf = unpack8(vd);
#pragma unroll
    for (int i = 0; i < 8; ++i) part[i] += kf[i] * inv * vf[i];
  }
#pragma unroll
  for (int i = 0; i < 8; ++i) red[tid * 8 + i] = part[i];
  __syncthreads();
  if (tid < 32) {
    f32x8 s = (f32x8)0.f;
#pragma unroll
    for (int k = 0; k < 8; ++k)
#pragma unroll
      for (int i = 0; i < 8; ++i) s[i] += red[(tid + 32 * k) * 8 + i];
#pragma unroll
    for (int i = 0; i < 8; ++i)
      atomicAdd(&kv[b * 256 + seg * 8 + i], s[i]);
  }
}

// ------------------------------------------------- K2: crpe conv + combine
// template<K>. grid (HEADS, 64, 8). Block 256 = 16x16 pixels.
template <int K>
__global__ __launch_bounds__(256) void crpe_conv(
    const bf16* __restrict__ qT, const bf16* __restrict__ vT,
    const float* __restrict__ kvbuf, const float* __restrict__ wp,
    const float* __restrict__ bp, int OC, int hbase,
    bf16* __restrict__ mid) {
  constexpr int R = K / 2;
  constexpr int S = 16 + 2 * R;
  constexpr int NSLOT = 4 * ((S - 1) * 23 + 1);
  __shared__ __align__(16) char vs[NSLOT * 16];
  __shared__ float wlds[K * K * 32];
  __shared__ float blds[32];

  const int tid = threadIdx.x;
  const int hg = blockIdx.x;
  const int h = hbase + hg;
  const int tile = blockIdx.y;
  const int b = blockIdx.z;
  const int tx0 = (tile & 7) * 16, ty0 = (tile >> 3) * 16;
  const int px = tid & 15, py = tid >> 4;
  const int ocbase = hg * 32;

  for (int e = tid; e < S * S; e += 256) {
    const int ly = e / S, lx = e - ly * S;
    const int gy = ty0 - R + ly, gx = tx0 - R + lx;
    uint4 d0 = {0, 0, 0, 0}, d1 = {0, 0, 0, 0}, d2 = {0, 0, 0, 0},
          d3 = {0, 0, 0, 0};
    if (gy >= 0 && gy < 128 && gx >= 0 && gx < 128) {
      const uint4* src = (const uint4*)(vT +
          ((size_t)b * 16384 + gy * 128 + gx) * 256 + h * 32);
      d0 = src[0]; d1 = src[1]; d2 = src[2]; d3 = src[3];
    }
    const int p = ly * 22 + lx;
    const int sw = (p >> 1) & 3;
    char* base = vs + ((p << 2) << 4);
    *(uint4*)(base + ((0 ^ sw) << 4)) = d0;
    *(uint4*)(base + ((1 ^ sw) << 4)) = d1;
    *(uint4*)(base + ((2 ^ sw) << 4)) = d2;
    *(uint4*)(base + ((3 ^ sw) << 4)) = d3;
  }
  for (int e = tid; e < K * K * 32; e += 256)
    wlds[e] = wp[(e >> 5) * OC + ocbase + (e & 31)];
  if (tid < 32) blds[tid] = bp[ocbase + tid];
  __syncthreads();

  const float4* bl4 = (const float4*)blds;
  f32x8 acc[4];
#pragma unroll
  for (int cc = 0; cc < 4; ++cc) {
    const float4 b0 = bl4[cc * 2], b1 = bl4[cc * 2 + 1];
    acc[cc][0] = b0.x; acc[cc][1] = b0.y; acc[cc][2] = b0.z; acc[cc][3] = b0.w;
    acc[cc][4] = b1.x; acc[cc][5] = b1.y; acc[cc][6] = b1.z; acc[cc][7] = b1.w;
  }
  const float4* wlds4 = (const float4*)wlds;
#pragma unroll 1
  for (int ky = 0; ky < K; ++ky) {
#pragma unroll
    for (int kx = 0; kx < K; ++kx) {
      const int p = (py + ky) * 22 + (px + kx);
      const int tap = ky * K + kx;
      const int sw = (p >> 1) & 3;
      const char* base = vs + ((p << 2) << 4);
#pragma unroll
      for (int cc = 0; cc < 4; ++cc) {
        const uint4 vv = *(const uint4*)(base + ((cc ^ sw) << 4));
        const f32x8 vf = unpack8(vv);
        const float4 w0 = wlds4[tap * 8 + cc * 2];
        const float4 w1 = wlds4[tap * 8 + cc * 2 + 1];
        acc[cc][0] += vf[0] * w0.x; acc[cc][1] += vf[1] * w0.y;
        acc[cc][2] += vf[2] * w0.z; acc[cc][3] += vf[3] * w0.w;
        acc[cc][4] += vf[4] * w1.x; acc[cc][5] += vf[5] * w1.y;
        acc[cc][6] += vf[6] * w1.z; acc[cc][7] += vf[7] * w1.w;
      }
    }
  }

  const int n = (ty0 + py) * 128 + (tx0 + px);
  const size_t off = ((size_t)b * 16384 + n) * 256 + h * 32;
  const uint4* qsrc = (const uint4*)(qT + off);
  f32x8 qv[4];
  float ss = 0.f;
#pragma unroll
  for (int cc = 0; cc < 4; ++cc) {
    qv[cc] = unpack8(qsrc[cc]);
#pragma unroll
    for (int i = 0; i < 8; ++i) ss += qv[cc][i] * qv[cc][i];
  }
  const float qinv = rsqrtf(ss);
  const float4* kvp = (const float4*)(kvbuf + ((size_t)b * 8 + h) * 32);
  uint4* mdst = (uint4*)(mid + off);
#pragma unroll
  for (int cc = 0; cc < 4; ++cc) {
    const float4 ka = kvp[cc * 2], kb = kvp[cc * 2 + 1];
    float o[8];
    o[0] = SCALE_ * qv[cc][0] * qinv * ka.x + qv[cc][0] * acc[cc][0];
    o[1] = SCALE_ * qv[cc][1] * qinv * ka.y + qv[cc][1] * acc[cc][1];
    o[2] = SCALE_ * qv[cc][2] * qinv * ka.z + qv[cc][2] * acc[cc][2];
    o[3] = SCALE_ * qv[cc][3] * qinv * ka.w + qv[cc][3] * acc[cc][3];
    o[4] = SCALE_ * qv[cc][4] * qinv * kb.x + qv[cc][4] * acc[cc][4];
    o[5] = SCALE_ * qv[cc][5] * qinv * kb.y + qv[cc][5] * acc[cc][5];
    o[6] = SCALE_ * qv[cc][6] * qinv * kb.z + qv[cc][6] * acc[cc][6];
    o[7] = SCALE_ * qv[cc][7] * qinv * kb.w + qv[cc][7] * acc[cc][7];
    mdst[cc] = pack8(o[0], o[1], o[2], o[3], o[4], o[5], o[6], o[7]);
  }
}

// --------------------------------------------------------------- K3: proj MFMA
// grid (2, 1024), block 256. All gload16, dbuf, XCD swizzle.
// Epilogue: fp32 LDS transpose in 2x32KB chunks -> 512B-run stores.
__global__ __launch_bounds__(256) void proj_mfma(
    const bf16* __restrict__ mid, const bf16* __restrict__ wpT,
    const float* __restrict__ bproj, float* __restrict__ out) {
  __shared__ __align__(16) char LDSU[32768];
  char* As = LDSU;
  char* Bs = LDSU + 16384;
  const int tid = threadIdx.x;
  const int l = tid & 63, w = tid >> 6;
  const int wr = w >> 1, wc = w & 1;

  const int lin = blockIdx.y * 2 + blockIdx.x;
  const int xcd = lin & 7, qq = lin >> 3;
  const int jt = qq & 1;
  const int ttile = xcd * 128 + (qq >> 1);
  const int j0 = jt << 7;
  const int tk0 = ttile << 7;

  f32x4 acc[4][4];
#pragma unroll
  for (int m = 0; m < 4; ++m)
#pragma unroll
    for (int t = 0; t < 4; ++t) acc[m][t] = (f32x4){0.f, 0.f, 0.f, 0.f};

  const int row0 = w * 16 + (l >> 2), row1 = row0 + 64;
  const int sl = l & 3;
  const int sw0 = (row0 >> 1) & 3, sw1 = (row1 >> 1) & 3;
  const bf16* asrc0 = wpT + (size_t)(j0 + row0) * 256 + ((sl ^ sw0) << 3);
  const bf16* asrc1 = wpT + (size_t)(j0 + row1) * 256 + ((sl ^ sw1) << 3);
  const bf16* bsrc0 = mid + (size_t)(tk0 + row0) * 256 + ((sl ^ sw0) << 3);
  const bf16* bsrc1 = mid + (size_t)(tk0 + row1) * 256 + ((sl ^ sw1) << 3);
  const int d0 = w * 1024;
  const int d1 = 4096 + w * 1024;

  const int fr = l & 15;
  const int fq = l >> 4;
  const int fs = (fq ^ ((l >> 1) & 3)) << 4;

  gload16(asrc0, As + d0);
  gload16(asrc1, As + d1);
  gload16(bsrc0, Bs + d0);
  gload16(bsrc1, Bs + d1);
  __syncthreads();

  int cur = 0;
  for (int t = 0; t < 8; ++t) {
    const int kn = (t + 1) << 5;
    const int nxt = (cur ^ 1) << 13;
    if (t < 7) {
      gload16(asrc0 + kn, As + nxt + d0);
      gload16(asrc1 + kn, As + nxt + d1);
      gload16(bsrc0 + kn, Bs + nxt + d0);
      gload16(bsrc1 + kn, Bs + nxt + d1);
    }
    const char* Ac = As + (cur << 13);
    const char* Bc = Bs + (cur << 13);
    u16x8 af[4], bfv[4];
#pragma unroll
    for (int m = 0; m < 4; ++m)
      af[m] = *(const u16x8*)(Ac + (wr * 64 + m * 16 + fr) * 64 + fs);
#pragma unroll
    for (int tt = 0; tt < 4; ++tt)
      bfv[tt] = *(const u16x8*)(Bc + (wc * 64 + tt * 16 + fr) * 64 + fs);
#pragma unroll
    for (int m = 0; m < 4; ++m)
#pragma unroll
      for (int tt = 0; tt < 4; ++tt)
        acc[m][tt] = mfma16(af[m], bfv[tt], acc[m][tt]);
    __syncthreads();
    cur ^= 1;
  }

  // add bias into acc
#pragma unroll
  for (int m = 0; m < 4; ++m) {
    const float4 bias = *(const float4*)&bproj[j0 + wr * 64 + m * 16 + fq * 4];
#pragma unroll
    for (int t = 0; t < 4; ++t) {
      acc[m][t][0] += bias.x;
      acc[m][t][1] += bias.y;
      acc[m][t][2] += bias.z;
      acc[m][t][3] += bias.w;
    }
  }

  // epilogue: 2 chunks of 64 tokens, fp32 [ltok][128j] = 32KB each
  for (int chunk = 0; chunk < 2; ++chunk) {
    if (wc == chunk) {
#pragma unroll
      for (int m = 0; m < 4; ++m) {
        const int jq = wr * 16 + m * 4 + fq;  // 16B quad index (4 f32)
#pragma unroll
        for (int t = 0; t < 4; ++t) {
          const int ltok = t * 16 + fr;
          const int p = jq ^ (ltok & 15);
          float4 r;
          r.x = acc[m][t][0]; r.y = acc[m][t][1];
          r.z = acc[m][t][2]; r.w = acc[m][t][3];
          *(float4*)(LDSU + ltok * 512 + (p << 4)) = r;
        }
      }
    }
    __syncthreads();
    const int seg = tid & 31;
#pragma unroll
    for (int r = 0; r < 8; ++r) {
      const int ltok = r * 8 + (tid >> 5);
      const int p = seg ^ (ltok & 15);
      const float4 dv = *(const float4*)(LDSU + ltok * 512 + (p << 4));
      *(float4*)&out[(size_t)(tk0 + chunk * 64 + ltok) * 256 + j0 + seg * 4] = dv;
    }
    __syncthreads();
  }
}

// ------------------------------------------------------------------- launcher
extern "C" void kernel_launch(void* const* d_in, const int* in_sizes, int n_in,
                              void* d_out, int out_size, void* d_ws,
                              size_t ws_size, hipStream_t stream) {
  const float* x     = (const float*)d_in[0];
  const float* wqkv  = (const float*)d_in[1];
  const float* wproj = (const float*)d_in[2];
  const float* bproj = (const float*)d_in[3];
  const float* w3 = (const float*)d_in[4];
  const float* b3 = (const float*)d_in[5];
  const float* w5 = (const float*)d_in[6];
  const float* b5 = (const float*)d_in[7];
  const float* w7 = (const float*)d_in[8];
  const float* b7 = (const float*)d_in[9];
  float* out = (float*)d_out;

  const size_t PLANE = (size_t)8 * 16384 * 256;
  bf16* qT  = (bf16*)d_ws;
  bf16* vT  = qT + PLANE;
  bf16* kT  = vT + PLANE;
  bf16* mid = kT;                     // alias: k dead after kv_reduce
  float* kv = (float*)(kT + PLANE);
  bf16* wqkvT  = (bf16*)(kv + 2048);
  bf16* wprojT = wqkvT + 768 * 256;

  hipMemsetAsync(kv, 0, 2048 * sizeof(float), stream);
  prep_weights<<<dim3(768), 256, 0, stream>>>(wqkv, wproj, wqkvT, wprojT);
  qkv_mfma<<<dim3(6, 1024), 256, 0, stream>>>(x, wqkvT, qT, kT, vT);
  kv_reduce<<<dim3(64, 8), 256, 0, stream>>>(kT, vT, kv);
  crpe_conv<3><<<dim3(2, 64, 8), 256, 0, stream>>>(qT, vT, kv, w3, b3, 64, 0, mid);
  crpe_conv<5><<<dim3(3, 64, 8), 256, 0, stream>>>(qT, vT, kv, w5, b5, 96, 2, mid);
  crpe_conv<7><<<dim3(3, 64, 8), 256, 0, stream>>>(qT, vT, kv, w7, b7, 96, 5, mid);
  proj_mfma<<<dim3(2, 1024), 256, 0, stream>>>(mid, wprojT, bproj, out);
}